// Round 2
// baseline (2085.500 us; speedup 1.0000x reference)
//
#include <hip/hip_runtime.h>
#include <hip/hip_bf16.h>

#define NH 8
#define EMB 512
#define HDIM 64
#define SEQ 2048
#define VOCAB 8000
#define NTOK 4096
#define FFD 2048
#define LN_EPS 1e-5f
#define SM_SCALE 0.04419417382415922f   // 512^-0.5 (reference scales by E, not DH)

typedef unsigned short u16;
typedef short v8s __attribute__((ext_vector_type(8)));   // 8 bf16 in 4 VGPRs
typedef float v4f __attribute__((ext_vector_type(4)));   // MFMA accumulator

typedef const __attribute__((address_space(1))) void* gas_t;
typedef __attribute__((address_space(3))) void* las_t;

struct __align__(8) U16x4 { u16 x, y, z, w; };

__device__ __forceinline__ u16 f2bf(float x) {
    union { float f; unsigned int u; } c; c.f = x;
    return (u16)((c.u + 0x7FFFu + ((c.u >> 16) & 1u)) >> 16);   // RNE
}
__device__ __forceinline__ float bf2f(u16 b) {
    union { unsigned int u; float f; } c; c.u = ((unsigned int)b) << 16; return c.f;
}
__device__ __forceinline__ void splitbf(float x, u16& hi, u16& lo) {
    hi = f2bf(x);
    lo = f2bf(x - bf2f(hi));
}

// ---------------------------------------------------------------- embed
__global__ __launch_bounds__(128)
void embed_kernel(const int* __restrict__ tokens, const float* __restrict__ tok_emb,
                  const float* __restrict__ pos_emb, float* __restrict__ x)
{
    const int row = blockIdx.x;            // b*SEQ + t
    const int t   = row & (SEQ - 1);
    const int tok = tokens[row];
    const int c   = threadIdx.x * 4;
    const float4 a = *reinterpret_cast<const float4*>(tok_emb + (size_t)tok * EMB + c);
    const float4 p = *reinterpret_cast<const float4*>(pos_emb + (size_t)t * EMB + c);
    float4 r; r.x = a.x + p.x; r.y = a.y + p.y; r.z = a.z + p.z; r.w = a.w + p.w;
    *reinterpret_cast<float4*>(x + (size_t)row * EMB + c) = r;
}

// ---------------------------------------------------------------- weight transpose + bf16 hi/lo split
// src fp32 [R][C] row-major -> dst bf16 [Cp][R] (rows >= C zero-filled).
__global__ __launch_bounds__(256)
void transpose_split(const float* __restrict__ src, u16* __restrict__ dhi,
                     u16* __restrict__ dlo, int R, int C,
                     size_t sstride, size_t dstride)
{
    __shared__ float sh[32][33];
    const int z = blockIdx.z;
    src += (size_t)z * sstride; dhi += (size_t)z * dstride; dlo += (size_t)z * dstride;
    const int ct = blockIdx.x * 32, rt = blockIdx.y * 32;
    const int cx = threadIdx.x & 31, ry = threadIdx.x >> 5;  // ry 0..7
    #pragma unroll
    for (int i = 0; i < 4; ++i) {
        const int r = ry + i * 8;
        float v = 0.f;
        if (ct + cx < C) v = src[(size_t)(rt + r) * C + ct + cx];
        sh[r][cx] = v;
    }
    __syncthreads();
    #pragma unroll
    for (int i = 0; i < 4; ++i) {
        const int r = ry + i * 8;                 // out-row index within tile (orig col)
        u16 hi, lo; splitbf(sh[cx][r], hi, lo);
        const size_t o = (size_t)(ct + r) * R + rt + cx;
        dhi[o] = hi; dlo[o] = lo;
    }
}

// Wq/Wk/Wv [L,H,E,DH] -> qkvT[l][sel*512 + h*64 + d][e], bf16 hi/lo.
__global__ __launch_bounds__(256)
void transpose_qkv(const float* __restrict__ Wq, const float* __restrict__ Wk,
                   const float* __restrict__ Wv, u16* __restrict__ dhi,
                   u16* __restrict__ dlo)
{
    __shared__ float sh[32][33];
    const int z = blockIdx.z;                       // l*24 + sel*8 + h
    const int l = z / 24, rem = z % 24, sel = rem >> 3, h = rem & 7;
    const float* src = (sel == 0 ? Wq : sel == 1 ? Wk : Wv)
                       + ((size_t)(l * 8 + h)) * EMB * HDIM;
    const size_t dbase = ((size_t)l * 1536 + sel * 512 + h * 64) * EMB;
    const int ct = blockIdx.x * 32, rt = blockIdx.y * 32;   // ct<64, rt<512
    const int cx = threadIdx.x & 31, ry = threadIdx.x >> 5;
    #pragma unroll
    for (int i = 0; i < 4; ++i) {
        const int r = ry + i * 8;
        sh[r][cx] = src[(size_t)(rt + r) * HDIM + ct + cx];
    }
    __syncthreads();
    #pragma unroll
    for (int i = 0; i < 4; ++i) {
        const int r = ry + i * 8;
        u16 hi, lo; splitbf(sh[cx][r], hi, lo);
        const size_t o = dbase + (size_t)(ct + r) * EMB + rt + cx;
        dhi[o] = hi; dlo[o] = lo;
    }
}

// ---------------------------------------------------------------- layernorm -> bf16 hi/lo
__global__ __launch_bounds__(256)
void ln_split_kernel(const float* __restrict__ x, const float* __restrict__ g,
                     const float* __restrict__ b, u16* __restrict__ hhi,
                     u16* __restrict__ hlo)
{
    const int row  = blockIdx.x * 4 + (threadIdx.x >> 6);
    const int lane = threadIdx.x & 63;
    const float* xp = x + (size_t)row * EMB;
    const float4 v0 = *reinterpret_cast<const float4*>(xp + lane * 4);
    const float4 v1 = *reinterpret_cast<const float4*>(xp + lane * 4 + 256);

    float s = v0.x + v0.y + v0.z + v0.w + v1.x + v1.y + v1.z + v1.w;
    #pragma unroll
    for (int off = 32; off > 0; off >>= 1) s += __shfl_xor(s, off);
    const float mean = s * (1.0f / EMB);

    float dx[8] = {v0.x - mean, v0.y - mean, v0.z - mean, v0.w - mean,
                   v1.x - mean, v1.y - mean, v1.z - mean, v1.w - mean};
    float vs = 0.f;
    #pragma unroll
    for (int u = 0; u < 8; ++u) vs = fmaf(dx[u], dx[u], vs);
    #pragma unroll
    for (int off = 32; off > 0; off >>= 1) vs += __shfl_xor(vs, off);
    const float inv = 1.0f / sqrtf(vs * (1.0f / EMB) + LN_EPS);

    const float4 g0 = *reinterpret_cast<const float4*>(g + lane * 4);
    const float4 g1 = *reinterpret_cast<const float4*>(g + lane * 4 + 256);
    const float4 b0 = *reinterpret_cast<const float4*>(b + lane * 4);
    const float4 b1 = *reinterpret_cast<const float4*>(b + lane * 4 + 256);
    float ov[8];
    ov[0] = fmaf(dx[0] * inv, g0.x, b0.x); ov[1] = fmaf(dx[1] * inv, g0.y, b0.y);
    ov[2] = fmaf(dx[2] * inv, g0.z, b0.z); ov[3] = fmaf(dx[3] * inv, g0.w, b0.w);
    ov[4] = fmaf(dx[4] * inv, g1.x, b1.x); ov[5] = fmaf(dx[5] * inv, g1.y, b1.y);
    ov[6] = fmaf(dx[6] * inv, g1.z, b1.z); ov[7] = fmaf(dx[7] * inv, g1.w, b1.w);

    U16x4 h0, l0, h1, l1;
    splitbf(ov[0], h0.x, l0.x); splitbf(ov[1], h0.y, l0.y);
    splitbf(ov[2], h0.z, l0.z); splitbf(ov[3], h0.w, l0.w);
    splitbf(ov[4], h1.x, l1.x); splitbf(ov[5], h1.y, l1.y);
    splitbf(ov[6], h1.z, l1.z); splitbf(ov[7], h1.w, l1.w);
    const size_t o = (size_t)row * EMB + lane * 4;
    *reinterpret_cast<U16x4*>(hhi + o)       = h0;
    *reinterpret_cast<U16x4*>(hhi + o + 256) = h1;
    *reinterpret_cast<U16x4*>(hlo + o)       = l0;
    *reinterpret_cast<U16x4*>(hlo + o + 256) = l1;
}

// ---------------------------------------------------------------- split-bf16 MFMA GEMM
// A (hi/lo bf16) [M=4096][K] row-major; Bt (hi/lo bf16) [N][K] row-major (pre-transposed).
// C = A*B via 3-term split. BM = WMC*64, BN = 128, BK = 32. 256 threads = 4 waves.
// WMC=2: wave grid 2x2, 4x4 16x16 frags/wave. WMC=1: wave grid 1x4, 4x2 frags.
enum { EPI_QKV = 0, EPI_RES = 1, EPI_RELU_SPLIT = 2, EPI_OUT = 3 };

template<int WMC, int EPI>
__global__ __launch_bounds__(256)
void gemm_mfma(const u16* __restrict__ Ah, const u16* __restrict__ Al,
               const u16* __restrict__ Bh, const u16* __restrict__ Bl,
               const float* __restrict__ bias, int K, int N,
               float* o0, float* o1, float* o2,
               u16* __restrict__ u0, u16* __restrict__ u1)
{
    constexpr int BM = WMC * 64;
    constexpr int NFRAG = (WMC == 2) ? 4 : 2;
    constexpr int WSP = 16 * NFRAG;                 // per-wave n-span

    __shared__ __align__(16) u16 AhS[BM * 32], AlS[BM * 32];
    __shared__ __align__(16) u16 BhS[128 * 32], BlS[128 * 32];

    const int tid  = threadIdx.x;
    const int lane = tid & 63, w = tid >> 6;
    const int wm = (WMC == 2) ? (w >> 1) : 0;
    const int wn = (WMC == 2) ? (w & 1) : w;
    const int m0 = blockIdx.y * BM, n0 = blockIdx.x * 128;

    v4f acc[4][NFRAG];
    #pragma unroll
    for (int mi = 0; mi < 4; ++mi)
        #pragma unroll
        for (int ni = 0; ni < NFRAG; ++ni) acc[mi][ni] = (v4f)0.f;

    const int arow = lane & 15, kg = (lane >> 4) * 8;

    for (int k0 = 0; k0 < K; k0 += 32) {
        // stage A hi/lo (16B per lane, linear LDS dest = wave base + lane*16)
        #pragma unroll
        for (int u = 0; u < WMC; ++u) {
            const int ch = u * 256 + tid;
            const int r = ch >> 2, c8 = (ch & 3) * 8;
            const size_t go = (size_t)(m0 + r) * K + k0 + c8;
            __builtin_amdgcn_global_load_lds((gas_t)(Ah + go), (las_t)(AhS + ch * 8), 16, 0, 0);
            __builtin_amdgcn_global_load_lds((gas_t)(Al + go), (las_t)(AlS + ch * 8), 16, 0, 0);
        }
        // stage B hi/lo
        #pragma unroll
        for (int u = 0; u < 2; ++u) {
            const int ch = u * 256 + tid;
            const int r = ch >> 2, c8 = (ch & 3) * 8;
            const size_t go = (size_t)(n0 + r) * K + k0 + c8;
            __builtin_amdgcn_global_load_lds((gas_t)(Bh + go), (las_t)(BhS + ch * 8), 16, 0, 0);
            __builtin_amdgcn_global_load_lds((gas_t)(Bl + go), (las_t)(BlS + ch * 8), 16, 0, 0);
        }
        __syncthreads();

        v8s ah[4], al[4], bh[NFRAG], bl[NFRAG];
        #pragma unroll
        for (int mi = 0; mi < 4; ++mi) {
            const int idx = (wm * 64 + mi * 16 + arow) * 32 + kg;
            ah[mi] = *reinterpret_cast<const v8s*>(AhS + idx);
            al[mi] = *reinterpret_cast<const v8s*>(AlS + idx);
        }
        #pragma unroll
        for (int ni = 0; ni < NFRAG; ++ni) {
            const int idx = (wn * WSP + ni * 16 + arow) * 32 + kg;
            bh[ni] = *reinterpret_cast<const v8s*>(BhS + idx);
            bl[ni] = *reinterpret_cast<const v8s*>(BlS + idx);
        }
        #pragma unroll
        for (int mi = 0; mi < 4; ++mi)
            #pragma unroll
            for (int ni = 0; ni < NFRAG; ++ni) {
                acc[mi][ni] = __builtin_amdgcn_mfma_f32_16x16x32_bf16(ah[mi], bh[ni], acc[mi][ni], 0, 0, 0);
                acc[mi][ni] = __builtin_amdgcn_mfma_f32_16x16x32_bf16(ah[mi], bl[ni], acc[mi][ni], 0, 0, 0);
                acc[mi][ni] = __builtin_amdgcn_mfma_f32_16x16x32_bf16(al[mi], bh[ni], acc[mi][ni], 0, 0, 0);
            }
        __syncthreads();
    }

    // epilogue: C/D layout row=(lane>>4)*4+j, col=lane&15 [verified m89/m91]
    const int crow0 = (lane >> 4) * 4;
    const int ccol  = lane & 15;
    #pragma unroll
    for (int mi = 0; mi < 4; ++mi) {
        const int mbase = m0 + wm * 64 + mi * 16 + crow0;
        #pragma unroll
        for (int ni = 0; ni < NFRAG; ++ni) {
            const int n = n0 + wn * WSP + ni * 16 + ccol;
            if constexpr (EPI == EPI_QKV) {
                const int sel = n >> 9, hh = (n >> 6) & 7, dd = n & 63;
                float* dst = sel == 0 ? o0 : (sel == 1 ? o1 : o2);
                #pragma unroll
                for (int j = 0; j < 4; ++j) {
                    const int m = mbase + j;
                    dst[(((size_t)(m >> 11) * NH + hh) * SEQ + (m & (SEQ - 1))) * HDIM + dd]
                        = acc[mi][ni][j];
                }
            } else if constexpr (EPI == EPI_RES) {
                const float bv = bias[n];
                #pragma unroll
                for (int j = 0; j < 4; ++j) {
                    const size_t o = (size_t)(mbase + j) * N + n;
                    o0[o] = o0[o] + acc[mi][ni][j] + bv;
                }
            } else if constexpr (EPI == EPI_RELU_SPLIT) {
                const float bv = bias[n];
                #pragma unroll
                for (int j = 0; j < 4; ++j) {
                    const float v_ = fmaxf(acc[mi][ni][j] + bv, 0.f);
                    u16 hi, lo; splitbf(v_, hi, lo);
                    const size_t o = (size_t)(mbase + j) * N + n;
                    u0[o] = hi; u1[o] = lo;
                }
            } else {                                    // EPI_OUT (LM head, ragged N)
                if (n < N) {
                    const float bv = bias[n];
                    #pragma unroll
                    for (int j = 0; j < 4; ++j)
                        o0[(size_t)(mbase + j) * N + n] = acc[mi][ni][j] + bv;
                }
            }
        }
    }
}

// ---------------------------------------------------------------- causal flash attention (fp32)
// grid (32, 16): y = b*NH+h, x -> qt reversed. Epilogue emits bf16 hi/lo (O-proj A operand).
__global__ __launch_bounds__(256)
void attn_kernel(const float* __restrict__ q, const float* __restrict__ k,
                 const float* __restrict__ v, u16* __restrict__ ohi,
                 u16* __restrict__ olo)
{
    const int bh = blockIdx.y;
    const int qt = 31 - blockIdx.x;
    const int bb = bh >> 3, hh = bh & 7;
    const int tid = threadIdx.x;
    const int tx = tid & 15, ty = tid >> 4;

    __shared__ float Qs[64][64];  // [d][r]
    __shared__ float Ks[64][64];  // [d][c]
    __shared__ float Vs[64][64];  // [c][d]
    __shared__ float Ps[64][64];  // [r][c]

    {
        const int r = tid >> 2, d0 = (tid & 3) * 16;
        const float* src = q + ((size_t)bh * SEQ + qt * 64 + r) * HDIM + d0;
        #pragma unroll
        for (int u = 0; u < 4; ++u) {
            const float4 t4 = *reinterpret_cast<const float4*>(src + 4 * u);
            Qs[d0 + 4 * u + 0][r] = t4.x; Qs[d0 + 4 * u + 1][r] = t4.y;
            Qs[d0 + 4 * u + 2][r] = t4.z; Qs[d0 + 4 * u + 3][r] = t4.w;
        }
    }

    float m_r[4], l_r[4], oa[4][4];
    #pragma unroll
    for (int i = 0; i < 4; ++i) {
        m_r[i] = -3.0e38f; l_r[i] = 0.f;
        #pragma unroll
        for (int j = 0; j < 4; ++j) oa[i][j] = 0.f;
    }
    const float* kb = k + (size_t)bh * SEQ * HDIM;
    const float* vb = v + (size_t)bh * SEQ * HDIM;

    for (int kt = 0; kt <= qt; ++kt) {
        __syncthreads();
        {
            const int r = tid >> 2, d0 = (tid & 3) * 16;
            const float* ks = kb + ((size_t)kt * 64 + r) * HDIM + d0;
            const float* vs = vb + ((size_t)kt * 64 + r) * HDIM + d0;
            #pragma unroll
            for (int u = 0; u < 4; ++u) {
                const float4 t4 = *reinterpret_cast<const float4*>(ks + 4 * u);
                Ks[d0 + 4 * u + 0][r] = t4.x; Ks[d0 + 4 * u + 1][r] = t4.y;
                Ks[d0 + 4 * u + 2][r] = t4.z; Ks[d0 + 4 * u + 3][r] = t4.w;
                *reinterpret_cast<float4*>(&Vs[r][d0 + 4 * u]) =
                    *reinterpret_cast<const float4*>(vs + 4 * u);
            }
        }
        __syncthreads();

        float s[4][4];
        #pragma unroll
        for (int i = 0; i < 4; ++i)
            #pragma unroll
            for (int j = 0; j < 4; ++j) s[i][j] = 0.f;

        #pragma unroll 8
        for (int d = 0; d < 64; ++d) {
            const float4 a4 = *reinterpret_cast<const float4*>(&Qs[d][ty * 4]);
            const float4 c4 = *reinterpret_cast<const float4*>(&Ks[d][tx * 4]);
            const float av[4] = {a4.x, a4.y, a4.z, a4.w};
            const float cv[4] = {c4.x, c4.y, c4.z, c4.w};
            #pragma unroll
            for (int i = 0; i < 4; ++i)
                #pragma unroll
                for (int j = 0; j < 4; ++j)
                    s[i][j] = fmaf(av[i], cv[j], s[i][j]);
        }

        if (kt == qt) {
            #pragma unroll
            for (int i = 0; i < 4; ++i)
                #pragma unroll
                for (int j = 0; j < 4; ++j)
                    s[i][j] = (tx * 4 + j <= ty * 4 + i) ? s[i][j] * SM_SCALE : -3.0e38f;
        } else {
            #pragma unroll
            for (int i = 0; i < 4; ++i)
                #pragma unroll
                for (int j = 0; j < 4; ++j) s[i][j] *= SM_SCALE;
        }

        float p_[4][4];
        #pragma unroll
        for (int i = 0; i < 4; ++i) {
            float rm = fmaxf(fmaxf(s[i][0], s[i][1]), fmaxf(s[i][2], s[i][3]));
            #pragma unroll
            for (int off = 1; off < 16; off <<= 1) rm = fmaxf(rm, __shfl_xor(rm, off));
            const float nm = fmaxf(m_r[i], rm);
            const float sc = __expf(m_r[i] - nm);
            m_r[i] = nm;
            float rs = 0.f;
            #pragma unroll
            for (int j = 0; j < 4; ++j) { p_[i][j] = __expf(s[i][j] - nm); rs += p_[i][j]; }
            #pragma unroll
            for (int off = 1; off < 16; off <<= 1) rs += __shfl_xor(rs, off);
            l_r[i] = l_r[i] * sc + rs;
            #pragma unroll
            for (int j = 0; j < 4; ++j) oa[i][j] *= sc;
        }
        #pragma unroll
        for (int i = 0; i < 4; ++i) {
            float4 v_; v_.x = p_[i][0]; v_.y = p_[i][1]; v_.z = p_[i][2]; v_.w = p_[i][3];
            *reinterpret_cast<float4*>(&Ps[ty * 4 + i][tx * 4]) = v_;
        }
        __syncthreads();

        #pragma unroll 8
        for (int c = 0; c < 64; ++c) {
            const float pa[4] = {Ps[ty * 4 + 0][c], Ps[ty * 4 + 1][c],
                                 Ps[ty * 4 + 2][c], Ps[ty * 4 + 3][c]};
            const float4 v4 = *reinterpret_cast<const float4*>(&Vs[c][tx * 4]);
            const float vv[4] = {v4.x, v4.y, v4.z, v4.w};
            #pragma unroll
            for (int i = 0; i < 4; ++i)
                #pragma unroll
                for (int j = 0; j < 4; ++j)
                    oa[i][j] = fmaf(pa[i], vv[j], oa[i][j]);
        }
    }

    #pragma unroll
    for (int i = 0; i < 4; ++i) {
        const float inv = 1.0f / l_r[i];
        U16x4 hv, lv;
        splitbf(oa[i][0] * inv, hv.x, lv.x);
        splitbf(oa[i][1] * inv, hv.y, lv.y);
        splitbf(oa[i][2] * inv, hv.z, lv.z);
        splitbf(oa[i][3] * inv, hv.w, lv.w);
        const size_t row = (size_t)bb * SEQ + qt * 64 + ty * 4 + i;
        const size_t o = row * EMB + hh * HDIM + tx * 4;
        *reinterpret_cast<U16x4*>(ohi + o) = hv;
        *reinterpret_cast<U16x4*>(olo + o) = lv;
    }
}

// ---------------------------------------------------------------- launch
extern "C" void kernel_launch(void* const* d_in, const int* in_sizes, int n_in,
                              void* d_out, int out_size, void* d_ws, size_t ws_size,
                              hipStream_t stream)
{
    const int*   tokens  = (const int*)  d_in[0];
    const float* tok_emb = (const float*)d_in[1];
    const float* pos_emb = (const float*)d_in[2];
    const float* Wq      = (const float*)d_in[3];
    const float* Wk      = (const float*)d_in[4];
    const float* Wv      = (const float*)d_in[5];
    const float* Wo      = (const float*)d_in[6];
    const float* bo      = (const float*)d_in[7];
    const float* ln1_g   = (const float*)d_in[8];
    const float* ln1_b   = (const float*)d_in[9];
    const float* ln2_g   = (const float*)d_in[10];
    const float* ln2_b   = (const float*)d_in[11];
    const float* W1      = (const float*)d_in[12];
    const float* b1      = (const float*)d_in[13];
    const float* W2      = (const float*)d_in[14];
    const float* b2      = (const float*)d_in[15];
    const float* lnf_g   = (const float*)d_in[16];
    const float* lnf_b   = (const float*)d_in[17];
    const float* Wlm     = (const float*)d_in[18];
    const float* blm     = (const float*)d_in[19];
    float* out = (float*)d_out;

    // workspace (~115 MB):
    // x fp32 (8MB) | Z 32MB {q,k,v fp32; o hi/lo bf16} aliased by {ff hi/lo bf16}
    // | h hi/lo bf16 (8MB) | transposed split weights (~67MB)
    const size_t NE = (size_t)NTOK * EMB;            // 2097152
    const size_t NF = (size_t)NTOK * FFD;            // 8388608
    float* x   = (float*)d_ws;
    float* zr  = x + NE;
    float* qb  = zr;
    float* kb  = zr + NE;
    float* vb  = zr + 2 * NE;
    u16* ohi   = (u16*)(zr + 3 * NE);
    u16* olo   = ohi + NE;
    u16* ffhi  = (u16*)zr;                           // alias over q..o
    u16* fflo  = ffhi + NF;
    u16* hhi   = (u16*)(zr + 4 * NE);
    u16* hlo   = hhi + NE;

    const size_t SQKV = (size_t)4 * 1536 * 512;
    const size_t SWO  = (size_t)4 * 512 * 512;
    const size_t SW1  = (size_t)4 * 2048 * 512;
    const size_t SLM  = (size_t)8064 * 512;
    u16* qkvT_h = hlo + NE;        u16* qkvT_l = qkvT_h + SQKV;
    u16* woT_h  = qkvT_l + SQKV;   u16* woT_l  = woT_h + SWO;
    u16* w1T_h  = woT_l + SWO;     u16* w1T_l  = w1T_h + SW1;
    u16* w2T_h  = w1T_l + SW1;     u16* w2T_l  = w2T_h + SW1;
    u16* wlmT_h = w2T_l + SW1;     u16* wlmT_l = wlmT_h + SLM;

    // ---- weight prep (every call; ws is re-poisoned by harness) ----
    transpose_qkv<<<dim3(2, 16, 96), 256, 0, stream>>>(Wq, Wk, Wv, qkvT_h, qkvT_l);
    transpose_split<<<dim3(16, 16, 4), 256, 0, stream>>>(Wo, woT_h, woT_l, 512, 512,
                                                         262144, 262144);
    transpose_split<<<dim3(64, 16, 4), 256, 0, stream>>>(W1, w1T_h, w1T_l, 512, 2048,
                                                         1048576, 1048576);
    transpose_split<<<dim3(16, 64, 4), 256, 0, stream>>>(W2, w2T_h, w2T_l, 2048, 512,
                                                         1048576, 1048576);
    transpose_split<<<dim3(252, 16, 1), 256, 0, stream>>>(Wlm, wlmT_h, wlmT_l, 512, 8000,
                                                          0, 0);

    embed_kernel<<<NTOK, 128, 0, stream>>>(tokens, tok_emb, pos_emb, x);

    for (int l = 0; l < 4; ++l) {
        ln_split_kernel<<<NTOK / 4, 256, 0, stream>>>(x, ln1_g + l * EMB, ln1_b + l * EMB,
                                                      hhi, hlo);
        gemm_mfma<2, EPI_QKV><<<dim3(12, 32), 256, 0, stream>>>(
            hhi, hlo, qkvT_h + (size_t)l * 1536 * 512, qkvT_l + (size_t)l * 1536 * 512,
            nullptr, EMB, 1536, qb, kb, vb, nullptr, nullptr);

        attn_kernel<<<dim3(32, 16), 256, 0, stream>>>(qb, kb, vb, ohi, olo);

        gemm_mfma<1, EPI_RES><<<dim3(4, 64), 256, 0, stream>>>(
            ohi, olo, woT_h + (size_t)l * 262144, woT_l + (size_t)l * 262144,
            bo + l * EMB, EMB, EMB, x, nullptr, nullptr, nullptr, nullptr);

        ln_split_kernel<<<NTOK / 4, 256, 0, stream>>>(x, ln2_g + l * EMB, ln2_b + l * EMB,
                                                      hhi, hlo);
        gemm_mfma<2, EPI_RELU_SPLIT><<<dim3(16, 32), 256, 0, stream>>>(
            hhi, hlo, w1T_h + (size_t)l * 1048576, w1T_l + (size_t)l * 1048576,
            b1 + l * FFD, EMB, FFD, nullptr, nullptr, nullptr, ffhi, fflo);

        gemm_mfma<1, EPI_RES><<<dim3(4, 64), 256, 0, stream>>>(
            ffhi, fflo, w2T_h + (size_t)l * 1048576, w2T_l + (size_t)l * 1048576,
            b2 + l * EMB, FFD, EMB, x, nullptr, nullptr, nullptr, nullptr);
    }

    ln_split_kernel<<<NTOK / 4, 256, 0, stream>>>(x, lnf_g, lnf_b, hhi, hlo);

    gemm_mfma<2, EPI_OUT><<<dim3(63, 32), 256, 0, stream>>>(
        hhi, hlo, wlmT_h, wlmT_l, blm, EMB, VOCAB, out, nullptr, nullptr,
        nullptr, nullptr);
}

// Round 5
// 1300.100 us; speedup vs baseline: 1.6041x; 1.6041x over previous
//
#include <hip/hip_runtime.h>
#include <hip/hip_bf16.h>

#define NH 8
#define EMB 512
#define HDIM 64
#define SEQ 2048
#define VOCAB 8000
#define NTOK 4096
#define FFD 2048
#define LN_EPS 1e-5f
#define SM_SCALE 0.04419417382415922f   // 512^-0.5 (reference scales by E, not DH)

typedef unsigned short u16;
typedef unsigned int u32;
typedef short v8s __attribute__((ext_vector_type(8)));   // 8 bf16 in 4 VGPRs
typedef float v4f __attribute__((ext_vector_type(4)));   // MFMA accumulator

typedef const __attribute__((address_space(1))) void* gas_t;
typedef __attribute__((address_space(3))) void* las_t;

struct __align__(8) U16x4 { u16 x, y, z, w; };

__device__ __forceinline__ u16 f2bf(float x) {
    union { float f; unsigned int u; } c; c.f = x;
    return (u16)((c.u + 0x7FFFu + ((c.u >> 16) & 1u)) >> 16);   // RNE
}
__device__ __forceinline__ float bf2f(u16 b) {
    union { unsigned int u; float f; } c; c.u = ((unsigned int)b) << 16; return c.f;
}
__device__ __forceinline__ void splitbf(float x, u16& hi, u16& lo) {
    hi = f2bf(x);
    lo = f2bf(x - bf2f(hi));
}

// ---------------------------------------------------------------- embed
__global__ __launch_bounds__(128)
void embed_kernel(const int* __restrict__ tokens, const float* __restrict__ tok_emb,
                  const float* __restrict__ pos_emb, float* __restrict__ x)
{
    const int row = blockIdx.x;            // b*SEQ + t
    const int t   = row & (SEQ - 1);
    const int tok = tokens[row];
    const int c   = threadIdx.x * 4;
    const float4 a = *reinterpret_cast<const float4*>(tok_emb + (size_t)tok * EMB + c);
    const float4 p = *reinterpret_cast<const float4*>(pos_emb + (size_t)t * EMB + c);
    float4 r; r.x = a.x + p.x; r.y = a.y + p.y; r.z = a.z + p.z; r.w = a.w + p.w;
    *reinterpret_cast<float4*>(x + (size_t)row * EMB + c) = r;
}

// ---------------------------------------------------------------- weight transpose + bf16 hi/lo split
__global__ __launch_bounds__(256)
void transpose_split(const float* __restrict__ src, u16* __restrict__ dhi,
                     u16* __restrict__ dlo, int R, int C,
                     size_t sstride, size_t dstride)
{
    __shared__ float sh[32][33];
    const int z = blockIdx.z;
    src += (size_t)z * sstride; dhi += (size_t)z * dstride; dlo += (size_t)z * dstride;
    const int ct = blockIdx.x * 32, rt = blockIdx.y * 32;
    const int cx = threadIdx.x & 31, ry = threadIdx.x >> 5;  // ry 0..7
    #pragma unroll
    for (int i = 0; i < 4; ++i) {
        const int r = ry + i * 8;
        float v = 0.f;
        if (ct + cx < C) v = src[(size_t)(rt + r) * C + ct + cx];
        sh[r][cx] = v;
    }
    __syncthreads();
    #pragma unroll
    for (int i = 0; i < 4; ++i) {
        const int r = ry + i * 8;
        u16 hi, lo; splitbf(sh[cx][r], hi, lo);
        const size_t o = (size_t)(ct + r) * R + rt + cx;
        dhi[o] = hi; dlo[o] = lo;
    }
}

// Wq/Wk/Wv [L,H,E,DH] -> qkvT[l][sel*512 + h*64 + d][e], bf16 hi/lo.
__global__ __launch_bounds__(256)
void transpose_qkv(const float* __restrict__ Wq, const float* __restrict__ Wk,
                   const float* __restrict__ Wv, u16* __restrict__ dhi,
                   u16* __restrict__ dlo)
{
    __shared__ float sh[32][33];
    const int z = blockIdx.z;                       // l*24 + sel*8 + h
    const int l = z / 24, rem = z % 24, sel = rem >> 3, h = rem & 7;
    const float* src = (sel == 0 ? Wq : sel == 1 ? Wk : Wv)
                       + ((size_t)(l * 8 + h)) * EMB * HDIM;
    const size_t dbase = ((size_t)l * 1536 + sel * 512 + h * 64) * EMB;
    const int ct = blockIdx.x * 32, rt = blockIdx.y * 32;   // ct<64, rt<512
    const int cx = threadIdx.x & 31, ry = threadIdx.x >> 5;
    #pragma unroll
    for (int i = 0; i < 4; ++i) {
        const int r = ry + i * 8;
        sh[r][cx] = src[(size_t)(rt + r) * HDIM + ct + cx];
    }
    __syncthreads();
    #pragma unroll
    for (int i = 0; i < 4; ++i) {
        const int r = ry + i * 8;
        u16 hi, lo; splitbf(sh[cx][r], hi, lo);
        const size_t o = dbase + (size_t)(ct + r) * EMB + rt + cx;
        dhi[o] = hi; dlo[o] = lo;
    }
}

// ---------------------------------------------------------------- layernorm -> bf16 hi/lo
__global__ __launch_bounds__(256)
void ln_split_kernel(const float* __restrict__ x, const float* __restrict__ g,
                     const float* __restrict__ b, u16* __restrict__ hhi,
                     u16* __restrict__ hlo)
{
    const int row  = blockIdx.x * 4 + (threadIdx.x >> 6);
    const int lane = threadIdx.x & 63;
    const float* xp = x + (size_t)row * EMB;
    const float4 v0 = *reinterpret_cast<const float4*>(xp + lane * 4);
    const float4 v1 = *reinterpret_cast<const float4*>(xp + lane * 4 + 256);

    float s = v0.x + v0.y + v0.z + v0.w + v1.x + v1.y + v1.z + v1.w;
    #pragma unroll
    for (int off = 32; off > 0; off >>= 1) s += __shfl_xor(s, off);
    const float mean = s * (1.0f / EMB);

    float dx[8] = {v0.x - mean, v0.y - mean, v0.z - mean, v0.w - mean,
                   v1.x - mean, v1.y - mean, v1.z - mean, v1.w - mean};
    float vs = 0.f;
    #pragma unroll
    for (int u = 0; u < 8; ++u) vs = fmaf(dx[u], dx[u], vs);
    #pragma unroll
    for (int off = 32; off > 0; off >>= 1) vs += __shfl_xor(vs, off);
    const float inv = 1.0f / sqrtf(vs * (1.0f / EMB) + LN_EPS);

    const float4 g0 = *reinterpret_cast<const float4*>(g + lane * 4);
    const float4 g1 = *reinterpret_cast<const float4*>(g + lane * 4 + 256);
    const float4 b0 = *reinterpret_cast<const float4*>(b + lane * 4);
    const float4 b1 = *reinterpret_cast<const float4*>(b + lane * 4 + 256);
    float ov[8];
    ov[0] = fmaf(dx[0] * inv, g0.x, b0.x); ov[1] = fmaf(dx[1] * inv, g0.y, b0.y);
    ov[2] = fmaf(dx[2] * inv, g0.z, b0.z); ov[3] = fmaf(dx[3] * inv, g0.w, b0.w);
    ov[4] = fmaf(dx[4] * inv, g1.x, b1.x); ov[5] = fmaf(dx[5] * inv, g1.y, b1.y);
    ov[6] = fmaf(dx[6] * inv, g1.z, b1.z); ov[7] = fmaf(dx[7] * inv, g1.w, b1.w);

    U16x4 h0, l0, h1, l1;
    splitbf(ov[0], h0.x, l0.x); splitbf(ov[1], h0.y, l0.y);
    splitbf(ov[2], h0.z, l0.z); splitbf(ov[3], h0.w, l0.w);
    splitbf(ov[4], h1.x, l1.x); splitbf(ov[5], h1.y, l1.y);
    splitbf(ov[6], h1.z, l1.z); splitbf(ov[7], h1.w, l1.w);
    const size_t o = (size_t)row * EMB + lane * 4;
    *reinterpret_cast<U16x4*>(hhi + o)       = h0;
    *reinterpret_cast<U16x4*>(hhi + o + 256) = h1;
    *reinterpret_cast<U16x4*>(hlo + o)       = l0;
    *reinterpret_cast<U16x4*>(hlo + o + 256) = l1;
}

// ---------------------------------------------------------------- split-bf16 MFMA GEMM
// A (hi/lo bf16) [M=4096][K] row-major; Bt (hi/lo bf16) [N][K] row-major.
enum { EPI_QKV = 0, EPI_RES = 1, EPI_RELU_SPLIT = 2, EPI_OUT = 3 };

template<int WMC, int EPI>
__global__ __launch_bounds__(256)
void gemm_mfma(const u16* __restrict__ Ah, const u16* __restrict__ Al,
               const u16* __restrict__ Bh, const u16* __restrict__ Bl,
               const float* __restrict__ bias, int K, int N,
               float* o0,
               u16* __restrict__ u0, u16* __restrict__ u1, u16* __restrict__ u2)
{
    constexpr int BM = WMC * 64;
    constexpr int NFRAG = (WMC == 2) ? 4 : 2;
    constexpr int WSP = 16 * NFRAG;                 // per-wave n-span

    __shared__ __align__(16) u16 AhS[BM * 32], AlS[BM * 32];
    __shared__ __align__(16) u16 BhS[128 * 32], BlS[128 * 32];

    const int tid  = threadIdx.x;
    const int lane = tid & 63, w = tid >> 6;
    const int wm = (WMC == 2) ? (w >> 1) : 0;
    const int wn = (WMC == 2) ? (w & 1) : w;
    const int m0 = blockIdx.y * BM, n0 = blockIdx.x * 128;

    v4f acc[4][NFRAG];
    #pragma unroll
    for (int mi = 0; mi < 4; ++mi)
        #pragma unroll
        for (int ni = 0; ni < NFRAG; ++ni) acc[mi][ni] = (v4f)0.f;

    const int arow = lane & 15, kg = (lane >> 4) * 8;

    for (int k0 = 0; k0 < K; k0 += 32) {
        #pragma unroll
        for (int u = 0; u < WMC; ++u) {
            const int ch = u * 256 + tid;
            const int r = ch >> 2, c8 = (ch & 3) * 8;
            const size_t go = (size_t)(m0 + r) * K + k0 + c8;
            __builtin_amdgcn_global_load_lds((gas_t)(Ah + go), (las_t)(AhS + ch * 8), 16, 0, 0);
            __builtin_amdgcn_global_load_lds((gas_t)(Al + go), (las_t)(AlS + ch * 8), 16, 0, 0);
        }
        #pragma unroll
        for (int u = 0; u < 2; ++u) {
            const int ch = u * 256 + tid;
            const int r = ch >> 2, c8 = (ch & 3) * 8;
            const size_t go = (size_t)(n0 + r) * K + k0 + c8;
            __builtin_amdgcn_global_load_lds((gas_t)(Bh + go), (las_t)(BhS + ch * 8), 16, 0, 0);
            __builtin_amdgcn_global_load_lds((gas_t)(Bl + go), (las_t)(BlS + ch * 8), 16, 0, 0);
        }
        __syncthreads();

        v8s ah[4], al[4], bh[NFRAG], bl[NFRAG];
        #pragma unroll
        for (int mi = 0; mi < 4; ++mi) {
            const int idx = (wm * 64 + mi * 16 + arow) * 32 + kg;
            ah[mi] = *reinterpret_cast<const v8s*>(AhS + idx);
            al[mi] = *reinterpret_cast<const v8s*>(AlS + idx);
        }
        #pragma unroll
        for (int ni = 0; ni < NFRAG; ++ni) {
            const int idx = (wn * WSP + ni * 16 + arow) * 32 + kg;
            bh[ni] = *reinterpret_cast<const v8s*>(BhS + idx);
            bl[ni] = *reinterpret_cast<const v8s*>(BlS + idx);
        }
        #pragma unroll
        for (int mi = 0; mi < 4; ++mi)
            #pragma unroll
            for (int ni = 0; ni < NFRAG; ++ni) {
                acc[mi][ni] = __builtin_amdgcn_mfma_f32_16x16x32_bf16(ah[mi], bh[ni], acc[mi][ni], 0, 0, 0);
                acc[mi][ni] = __builtin_amdgcn_mfma_f32_16x16x32_bf16(ah[mi], bl[ni], acc[mi][ni], 0, 0, 0);
                acc[mi][ni] = __builtin_amdgcn_mfma_f32_16x16x32_bf16(al[mi], bh[ni], acc[mi][ni], 0, 0, 0);
            }
        __syncthreads();
    }

    // epilogue: C/D layout row=(lane>>4)*4+j, col=lane&15
    const int crow0 = (lane >> 4) * 4;
    const int ccol  = lane & 15;
    #pragma unroll
    for (int mi = 0; mi < 4; ++mi) {
        const int mbase = m0 + wm * 64 + mi * 16 + crow0;
        #pragma unroll
        for (int ni = 0; ni < NFRAG; ++ni) {
            const int n = n0 + wn * WSP + ni * 16 + ccol;
            if constexpr (EPI == EPI_QKV) {
                // q: bf16*SM_SCALE [B,H,T,D]; k: bf16 [B,H,T,D]; v: bf16 [B,H,D,T]
                const int sel = n >> 9, hh = (n >> 6) & 7, dd = n & 63;
                const int bbb = mbase >> 11, t = mbase & (SEQ - 1);
                if (sel == 2) {
                    U16x4 pv;
                    pv.x = f2bf(acc[mi][ni][0]); pv.y = f2bf(acc[mi][ni][1]);
                    pv.z = f2bf(acc[mi][ni][2]); pv.w = f2bf(acc[mi][ni][3]);
                    *reinterpret_cast<U16x4*>(
                        u2 + ((size_t)((bbb * NH + hh) * HDIM + dd) * SEQ + t)) = pv;
                } else {
                    u16* dst = sel ? u1 : u0;
                    const float scl = sel ? 1.0f : SM_SCALE;
                    #pragma unroll
                    for (int j = 0; j < 4; ++j) {
                        const int m = mbase + j;
                        dst[((size_t)((m >> 11) * NH + hh) * SEQ + (m & (SEQ - 1))) * HDIM + dd]
                            = f2bf(acc[mi][ni][j] * scl);
                    }
                }
            } else if constexpr (EPI == EPI_RES) {
                const float bv = bias[n];
                #pragma unroll
                for (int j = 0; j < 4; ++j) {
                    const size_t o = (size_t)(mbase + j) * N + n;
                    o0[o] = o0[o] + acc[mi][ni][j] + bv;
                }
            } else if constexpr (EPI == EPI_RELU_SPLIT) {
                const float bv = bias[n];
                #pragma unroll
                for (int j = 0; j < 4; ++j) {
                    const float v_ = fmaxf(acc[mi][ni][j] + bv, 0.f);
                    u16 hi, lo; splitbf(v_, hi, lo);
                    const size_t o = (size_t)(mbase + j) * N + n;
                    u0[o] = hi; u1[o] = lo;
                }
            } else {                                    // EPI_OUT (LM head, ragged N)
                if (n < N) {
                    const float bv = bias[n];
                    #pragma unroll
                    for (int j = 0; j < 4; ++j)
                        o0[(size_t)(mbase + j) * N + n] = acc[mi][ni][j] + bv;
                }
            }
        }
    }
}

// ---------------------------------------------------------------- MFMA flash attention
// 2 waves x 32 q rows = 64 q/block; grid (32 qt, 16 bh). bf16 Q(pre-scaled)/K/V.
// S^T = K*Q^T (per-lane softmax state); P via per-wave swizzled LDS; O^T = V^T*P^T.
// qt direction alternates with bh-half so co-resident block pairs are complementary.
__global__ __launch_bounds__(128)
void attn_mfma(const u16* __restrict__ qg, const u16* __restrict__ kg,
               const u16* __restrict__ vg, u16* __restrict__ ohi,
               u16* __restrict__ olo)
{
    __shared__ __align__(16) u16 KT[2][4096];   // swizzled [kv 64][d 64]
    __shared__ __align__(16) u16 VT[2][4096];   // swizzled [d 64][kv 64]
    __shared__ __align__(16) u16 PL[2][2048];   // per-wave, swizzled [q 32][kv 64]

    const int tid = threadIdx.x, lane = tid & 63, w = tid >> 6;
    const int g = lane >> 4, c = lane & 15;
    const int bh = blockIdx.y;
    const int qt = (bh & 8) ? (int)blockIdx.x : 31 - (int)blockIdx.x;  // load balance
    const int bb = bh >> 3, hh = bh & 7;

    const u16* qb = qg + (size_t)bh * (SEQ * HDIM);
    const u16* kb = kg + (size_t)bh * (SEQ * HDIM);
    const u16* vb = vg + (size_t)bh * (HDIM * SEQ);

    // staging chunk constants: chunk = w*256 + i*64 + lane; row=chunk>>3,
    // source slot pre-swizzled so LDS (linear dest) holds XOR-swizzled layout
    int soffK[4], soffV[4];
    #pragma unroll
    for (int i = 0; i < 4; ++i) {
        const int ch = w * 256 + i * 64 + lane;
        const int r = ch >> 3;
        const int sc_ = ((ch & 7) ^ (r & 7)) * 8;
        soffK[i] = r * HDIM + sc_;          // + kt*64*HDIM per iter
        soffV[i] = r * SEQ + sc_;           // + kt*64 per iter
    }

    // Q fragments (B-operand): lane holds Q[q=nf*16+c][d=ch*32+g*8 ..+7]
    v8s qreg[2][2];
    const int q0 = qt * 64 + w * 32;
    #pragma unroll
    for (int nf = 0; nf < 2; ++nf)
        #pragma unroll
        for (int ch = 0; ch < 2; ++ch)
            qreg[nf][ch] = *reinterpret_cast<const v8s*>(
                qb + (size_t)(q0 + nf * 16 + c) * HDIM + ch * 32 + g * 8);

    v4f oacc[4][2];
    #pragma unroll
    for (int mf = 0; mf < 4; ++mf)
        #pragma unroll
        for (int nf = 0; nf < 2; ++nf) oacc[mf][nf] = (v4f)0.f;
    float m_[2] = {-3.0e38f, -3.0e38f}, l_[2] = {0.f, 0.f};

    // prologue: stage kt=0 into buf 0
    #pragma unroll
    for (int i = 0; i < 4; ++i) {
        const int ch = w * 256 + i * 64 + lane;
        __builtin_amdgcn_global_load_lds((gas_t)(kb + soffK[i]), (las_t)(&KT[0][ch * 8]), 16, 0, 0);
        __builtin_amdgcn_global_load_lds((gas_t)(vb + soffV[i]), (las_t)(&VT[0][ch * 8]), 16, 0, 0);
    }
    __syncthreads();

    for (int kt = 0; kt <= qt; ++kt) {
        const int cur = kt & 1;
        if (kt < qt) {       // async-stage next tile into other buffer
            const int kn = kt + 1;
            #pragma unroll
            for (int i = 0; i < 4; ++i) {
                const int ch = w * 256 + i * 64 + lane;
                __builtin_amdgcn_global_load_lds((gas_t)(kb + (size_t)kn * 64 * HDIM + soffK[i]),
                                                 (las_t)(&KT[cur ^ 1][ch * 8]), 16, 0, 0);
                __builtin_amdgcn_global_load_lds((gas_t)(vb + (size_t)kn * 64 + soffV[i]),
                                                 (las_t)(&VT[cur ^ 1][ch * 8]), 16, 0, 0);
            }
        }

        // ---- S^T = K * Q^T ----
        v4f sacc[4][2];
        #pragma unroll
        for (int mf = 0; mf < 4; ++mf)
            #pragma unroll
            for (int nf = 0; nf < 2; ++nf) sacc[mf][nf] = (v4f)0.f;
        #pragma unroll
        for (int ch = 0; ch < 2; ++ch) {
            v8s kf[4];
            #pragma unroll
            for (int mf = 0; mf < 4; ++mf) {
                const int row = mf * 16 + c;
                int idx = row * 64 + ch * 32 + g * 8;
                idx ^= (row & 7) << 3;
                kf[mf] = *reinterpret_cast<const v8s*>(&KT[cur][idx]);
            }
            #pragma unroll
            for (int mf = 0; mf < 4; ++mf)
                #pragma unroll
                for (int nf = 0; nf < 2; ++nf)
                    sacc[mf][nf] = __builtin_amdgcn_mfma_f32_16x16x32_bf16(
                        kf[mf], qreg[nf][ch], sacc[mf][nf], 0, 0, 0);
        }

        // causal mask on diagonal tile
        if (kt == qt) {
            #pragma unroll
            for (int mf = 0; mf < 4; ++mf)
                #pragma unroll
                for (int nf = 0; nf < 2; ++nf)
                    #pragma unroll
                    for (int j = 0; j < 4; ++j) {
                        const int kvl = mf * 16 + g * 4 + j;
                        const int ql  = w * 32 + nf * 16 + c;
                        if (kvl > ql) sacc[mf][nf][j] = -3.0e38f;
                    }
        }

        // ---- online softmax (per-lane per nf) + P -> swizzled LDS ----
        #pragma unroll
        for (int nf = 0; nf < 2; ++nf) {
            float pmax = -3.0e38f;
            #pragma unroll
            for (int mf = 0; mf < 4; ++mf)
                #pragma unroll
                for (int j = 0; j < 4; ++j) pmax = fmaxf(pmax, sacc[mf][nf][j]);
            pmax = fmaxf(pmax, __shfl_xor(pmax, 16));
            pmax = fmaxf(pmax, __shfl_xor(pmax, 32));
            const float mnew = fmaxf(m_[nf], pmax);
            const float sc = __expf(m_[nf] - mnew);
            m_[nf] = mnew;
            float rs = 0.f;
            #pragma unroll
            for (int mf = 0; mf < 4; ++mf) {
                float p0 = __expf(sacc[mf][nf][0] - mnew);
                float p1 = __expf(sacc[mf][nf][1] - mnew);
                float p2 = __expf(sacc[mf][nf][2] - mnew);
                float p3 = __expf(sacc[mf][nf][3] - mnew);
                rs += (p0 + p1) + (p2 + p3);
                const u32 w0 = (u32)f2bf(p0) | ((u32)f2bf(p1) << 16);
                const u32 w1 = (u32)f2bf(p2) | ((u32)f2bf(p3) << 16);
                const int qrow = nf * 16 + c;                // 0..31
                int idx0 = qrow * 64 + mf * 16 + g * 4;      // kv even
                idx0 ^= (qrow & 7) << 3;
                *reinterpret_cast<u32*>(&PL[w][idx0]) = w0;
                int idx1 = qrow * 64 + mf * 16 + g * 4 + 2;
                idx1 ^= (qrow & 7) << 3;
                *reinterpret_cast<u32*>(&PL[w][idx1]) = w1;
            }
            rs += __shfl_xor(rs, 16);
            rs += __shfl_xor(rs, 32);
            l_[nf] = l_[nf] * sc + rs;
            #pragma unroll
            for (int mf = 0; mf < 4; ++mf)
                #pragma unroll
                for (int j = 0; j < 4; ++j) oacc[mf][nf][j] *= sc;
        }

        // ---- O^T += V^T * P^T ----
        #pragma unroll
        for (int ch = 0; ch < 2; ++ch) {
            v8s vf[4], pf[2];
            #pragma unroll
            for (int mf = 0; mf < 4; ++mf) {
                const int row = mf * 16 + c;                 // d row
                int idx = row * 64 + ch * 32 + g * 8;
                idx ^= (row & 7) << 3;
                vf[mf] = *reinterpret_cast<const v8s*>(&VT[cur][idx]);
            }
            #pragma unroll
            for (int nf = 0; nf < 2; ++nf) {
                const int qrow = nf * 16 + c;
                int idx = qrow * 64 + ch * 32 + g * 8;
                idx ^= (qrow & 7) << 3;
                pf[nf] = *reinterpret_cast<const v8s*>(&PL[w][idx]);
            }
            #pragma unroll
            for (int mf = 0; mf < 4; ++mf)
                #pragma unroll
                for (int nf = 0; nf < 2; ++nf)
                    oacc[mf][nf] = __builtin_amdgcn_mfma_f32_16x16x32_bf16(
                        vf[mf], pf[nf], oacc[mf][nf], 0, 0, 0);
        }
        __syncthreads();   // drains vmcnt (next tile staged) + protects buffers
    }

    // epilogue: O^T element (d = mf*16+g*4+j, q = nf*16+c); write hi/lo bf16
    #pragma unroll
    for (int nf = 0; nf < 2; ++nf) {
        const float inv = 1.0f / l_[nf];
        const size_t row = (size_t)bb * SEQ + q0 + nf * 16 + c;   // token
        #pragma unroll
        for (int mf = 0; mf < 4; ++mf) {
            float v0 = oacc[mf][nf][0] * inv, v1 = oacc[mf][nf][1] * inv;
            float v2 = oacc[mf][nf][2] * inv, v3 = oacc[mf][nf][3] * inv;
            U16x4 hv, lv;
            splitbf(v0, hv.x, lv.x); splitbf(v1, hv.y, lv.y);
            splitbf(v2, hv.z, lv.z); splitbf(v3, hv.w, lv.w);
            const size_t off = row * EMB + hh * HDIM + mf * 16 + g * 4;
            *reinterpret_cast<U16x4*>(ohi + off) = hv;
            *reinterpret_cast<U16x4*>(olo + off) = lv;
        }
    }
}

// ---------------------------------------------------------------- launch
extern "C" void kernel_launch(void* const* d_in, const int* in_sizes, int n_in,
                              void* d_out, int out_size, void* d_ws, size_t ws_size,
                              hipStream_t stream)
{
    const int*   tokens  = (const int*)  d_in[0];
    const float* tok_emb = (const float*)d_in[1];
    const float* pos_emb = (const float*)d_in[2];
    const float* Wq      = (const float*)d_in[3];
    const float* Wk      = (const float*)d_in[4];
    const float* Wv      = (const float*)d_in[5];
    const float* Wo      = (const float*)d_in[6];
    const float* bo      = (const float*)d_in[7];
    const float* ln1_g   = (const float*)d_in[8];
    const float* ln1_b   = (const float*)d_in[9];
    const float* ln2_g   = (const float*)d_in[10];
    const float* ln2_b   = (const float*)d_in[11];
    const float* W1      = (const float*)d_in[12];
    const float* b1      = (const float*)d_in[13];
    const float* W2      = (const float*)d_in[14];
    const float* b2      = (const float*)d_in[15];
    const float* lnf_g   = (const float*)d_in[16];
    const float* lnf_b   = (const float*)d_in[17];
    const float* Wlm     = (const float*)d_in[18];
    const float* blm     = (const float*)d_in[19];
    float* out = (float*)d_out;

    // workspace: x fp32 (8MB) | 32MB region {q,k,v,ohi,olo bf16 (20MB)} aliased
    // by {ff hi/lo bf16 (32MB)} | h hi/lo (8MB) | transposed split weights (~67MB)
    const size_t NE = (size_t)NTOK * EMB;            // 2097152
    const size_t NF = (size_t)NTOK * FFD;            // 8388608
    float* x   = (float*)d_ws;
    float* zr  = x + NE;
    u16* qb16  = (u16*)zr;
    u16* kb16  = qb16 + NE;
    u16* vb16  = kb16 + NE;                          // [B,H,D,T]
    u16* ohi   = vb16 + NE;
    u16* olo   = ohi + NE;
    u16* ffhi  = (u16*)zr;                           // aliases q..olo (disjoint lifetime)
    u16* fflo  = ffhi + NF;
    u16* hhi   = (u16*)(zr + 4 * NE);
    u16* hlo   = hhi + NE;

    const size_t SQKV = (size_t)4 * 1536 * 512;
    const size_t SWO  = (size_t)4 * 512 * 512;
    const size_t SW1  = (size_t)4 * 2048 * 512;
    const size_t SLM  = (size_t)8064 * 512;
    u16* qkvT_h = hlo + NE;        u16* qkvT_l = qkvT_h + SQKV;
    u16* woT_h  = qkvT_l + SQKV;   u16* woT_l  = woT_h + SWO;
    u16* w1T_h  = woT_l + SWO;     u16* w1T_l  = w1T_h + SW1;
    u16* w2T_h  = w1T_l + SW1;     u16* w2T_l  = w2T_h + SW1;
    u16* wlmT_h = w2T_l + SW1;     u16* wlmT_l = wlmT_h + SLM;

    // ---- weight prep (every call) ----
    transpose_qkv<<<dim3(2, 16, 96), 256, 0, stream>>>(Wq, Wk, Wv, qkvT_h, qkvT_l);
    transpose_split<<<dim3(16, 16, 4), 256, 0, stream>>>(Wo, woT_h, woT_l, 512, 512,
                                                         262144, 262144);
    transpose_split<<<dim3(64, 16, 4), 256, 0, stream>>>(W1, w1T_h, w1T_l, 512, 2048,
                                                         1048576, 1048576);
    transpose_split<<<dim3(16, 64, 4), 256, 0, stream>>>(W2, w2T_h, w2T_l, 2048, 512,
                                                         1048576, 1048576);
    transpose_split<<<dim3(252, 16, 1), 256, 0, stream>>>(Wlm, wlmT_h, wlmT_l, 512, 8000,
                                                          0, 0);

    embed_kernel<<<NTOK, 128, 0, stream>>>(tokens, tok_emb, pos_emb, x);

    for (int l = 0; l < 4; ++l) {
        ln_split_kernel<<<NTOK / 4, 256, 0, stream>>>(x, ln1_g + l * EMB, ln1_b + l * EMB,
                                                      hhi, hlo);
        gemm_mfma<2, EPI_QKV><<<dim3(12, 32), 256, 0, stream>>>(
            hhi, hlo, qkvT_h + (size_t)l * 1536 * 512, qkvT_l + (size_t)l * 1536 * 512,
            nullptr, EMB, 1536, nullptr, qb16, kb16, vb16);

        attn_mfma<<<dim3(32, 16), 128, 0, stream>>>(qb16, kb16, vb16, ohi, olo);

        gemm_mfma<1, EPI_RES><<<dim3(4, 64), 256, 0, stream>>>(
            ohi, olo, woT_h + (size_t)l * 262144, woT_l + (size_t)l * 262144,
            bo + l * EMB, EMB, EMB, x, nullptr, nullptr, nullptr);

        ln_split_kernel<<<NTOK / 4, 256, 0, stream>>>(x, ln2_g + l * EMB, ln2_b + l * EMB,
                                                      hhi, hlo);
        gemm_mfma<2, EPI_RELU_SPLIT><<<dim3(16, 32), 256, 0, stream>>>(
            hhi, hlo, w1T_h + (size_t)l * 1048576, w1T_l + (size_t)l * 1048576,
            b1 + l * FFD, EMB, FFD, nullptr, ffhi, fflo, nullptr);

        gemm_mfma<1, EPI_RES><<<dim3(4, 64), 256, 0, stream>>>(
            ffhi, fflo, w2T_h + (size_t)l * 1048576, w2T_l + (size_t)l * 1048576,
            b2 + l * EMB, FFD, EMB, x, nullptr, nullptr, nullptr);
    }

    ln_split_kernel<<<NTOK / 4, 256, 0, stream>>>(x, lnf_g, lnf_b, hhi, hlo);

    gemm_mfma<2, EPI_OUT><<<dim3(63, 32), 256, 0, stream>>>(
        hhi, hlo, wlmT_h, wlmT_l, blm, EMB, VOCAB, out, nullptr, nullptr, nullptr);
}

// Round 6
// 1188.735 us; speedup vs baseline: 1.7544x; 1.0937x over previous
//
#include <hip/hip_runtime.h>
#include <hip/hip_bf16.h>

#define NH 8
#define EMB 512
#define HDIM 64
#define SEQ 2048
#define VOCAB 8000
#define NTOK 4096
#define FFD 2048
#define LN_EPS 1e-5f
#define SM_SCALE 0.04419417382415922f   // 512^-0.5 (reference scales by E, not DH)

typedef unsigned short u16;
typedef unsigned int u32;
typedef short v8s __attribute__((ext_vector_type(8)));   // 8 bf16 in 4 VGPRs
typedef float v4f __attribute__((ext_vector_type(4)));   // MFMA accumulator

typedef const __attribute__((address_space(1))) void* gas_t;
typedef __attribute__((address_space(3))) void* las_t;

struct __align__(8) U16x4 { u16 x, y, z, w; };

__device__ __forceinline__ u16 f2bf(float x) {
    union { float f; unsigned int u; } c; c.f = x;
    return (u16)((c.u + 0x7FFFu + ((c.u >> 16) & 1u)) >> 16);   // RNE
}
__device__ __forceinline__ float bf2f(u16 b) {
    union { unsigned int u; float f; } c; c.u = ((unsigned int)b) << 16; return c.f;
}
__device__ __forceinline__ void splitbf(float x, u16& hi, u16& lo) {
    hi = f2bf(x);
    lo = f2bf(x - bf2f(hi));
}

// ---------------------------------------------------------------- embed
__global__ __launch_bounds__(128)
void embed_kernel(const int* __restrict__ tokens, const float* __restrict__ tok_emb,
                  const float* __restrict__ pos_emb, float* __restrict__ x)
{
    const int row = blockIdx.x;            // b*SEQ + t
    const int t   = row & (SEQ - 1);
    const int tok = tokens[row];
    const int c   = threadIdx.x * 4;
    const float4 a = *reinterpret_cast<const float4*>(tok_emb + (size_t)tok * EMB + c);
    const float4 p = *reinterpret_cast<const float4*>(pos_emb + (size_t)t * EMB + c);
    float4 r; r.x = a.x + p.x; r.y = a.y + p.y; r.z = a.z + p.z; r.w = a.w + p.w;
    *reinterpret_cast<float4*>(x + (size_t)row * EMB + c) = r;
}

// ---------------------------------------------------------------- weight transpose + bf16 hi/lo split
__global__ __launch_bounds__(256)
void transpose_split(const float* __restrict__ src, u16* __restrict__ dhi,
                     u16* __restrict__ dlo, int R, int C,
                     size_t sstride, size_t dstride)
{
    __shared__ float sh[32][33];
    const int z = blockIdx.z;
    src += (size_t)z * sstride; dhi += (size_t)z * dstride; dlo += (size_t)z * dstride;
    const int ct = blockIdx.x * 32, rt = blockIdx.y * 32;
    const int cx = threadIdx.x & 31, ry = threadIdx.x >> 5;  // ry 0..7
    #pragma unroll
    for (int i = 0; i < 4; ++i) {
        const int r = ry + i * 8;
        float v = 0.f;
        if (ct + cx < C) v = src[(size_t)(rt + r) * C + ct + cx];
        sh[r][cx] = v;
    }
    __syncthreads();
    #pragma unroll
    for (int i = 0; i < 4; ++i) {
        const int r = ry + i * 8;
        u16 hi, lo; splitbf(sh[cx][r], hi, lo);
        const size_t o = (size_t)(ct + r) * R + rt + cx;
        dhi[o] = hi; dlo[o] = lo;
    }
}

// Wq/Wk/Wv [L,H,E,DH] -> qkvT[l][sel*512 + h*64 + d][e], bf16 hi/lo.
__global__ __launch_bounds__(256)
void transpose_qkv(const float* __restrict__ Wq, const float* __restrict__ Wk,
                   const float* __restrict__ Wv, u16* __restrict__ dhi,
                   u16* __restrict__ dlo)
{
    __shared__ float sh[32][33];
    const int z = blockIdx.z;                       // l*24 + sel*8 + h
    const int l = z / 24, rem = z % 24, sel = rem >> 3, h = rem & 7;
    const float* src = (sel == 0 ? Wq : sel == 1 ? Wk : Wv)
                       + ((size_t)(l * 8 + h)) * EMB * HDIM;
    const size_t dbase = ((size_t)l * 1536 + sel * 512 + h * 64) * EMB;
    const int ct = blockIdx.x * 32, rt = blockIdx.y * 32;   // ct<64, rt<512
    const int cx = threadIdx.x & 31, ry = threadIdx.x >> 5;
    #pragma unroll
    for (int i = 0; i < 4; ++i) {
        const int r = ry + i * 8;
        sh[r][cx] = src[(size_t)(rt + r) * HDIM + ct + cx];
    }
    __syncthreads();
    #pragma unroll
    for (int i = 0; i < 4; ++i) {
        const int r = ry + i * 8;
        u16 hi, lo; splitbf(sh[cx][r], hi, lo);
        const size_t o = dbase + (size_t)(ct + r) * EMB + rt + cx;
        dhi[o] = hi; dlo[o] = lo;
    }
}

// ---------------------------------------------------------------- layernorm -> bf16 hi/lo
__global__ __launch_bounds__(256)
void ln_split_kernel(const float* __restrict__ x, const float* __restrict__ g,
                     const float* __restrict__ b, u16* __restrict__ hhi,
                     u16* __restrict__ hlo)
{
    const int row  = blockIdx.x * 4 + (threadIdx.x >> 6);
    const int lane = threadIdx.x & 63;
    const float* xp = x + (size_t)row * EMB;
    const float4 v0 = *reinterpret_cast<const float4*>(xp + lane * 4);
    const float4 v1 = *reinterpret_cast<const float4*>(xp + lane * 4 + 256);

    float s = v0.x + v0.y + v0.z + v0.w + v1.x + v1.y + v1.z + v1.w;
    #pragma unroll
    for (int off = 32; off > 0; off >>= 1) s += __shfl_xor(s, off);
    const float mean = s * (1.0f / EMB);

    float dx[8] = {v0.x - mean, v0.y - mean, v0.z - mean, v0.w - mean,
                   v1.x - mean, v1.y - mean, v1.z - mean, v1.w - mean};
    float vs = 0.f;
    #pragma unroll
    for (int u = 0; u < 8; ++u) vs = fmaf(dx[u], dx[u], vs);
    #pragma unroll
    for (int off = 32; off > 0; off >>= 1) vs += __shfl_xor(vs, off);
    const float inv = 1.0f / sqrtf(vs * (1.0f / EMB) + LN_EPS);

    const float4 g0 = *reinterpret_cast<const float4*>(g + lane * 4);
    const float4 g1 = *reinterpret_cast<const float4*>(g + lane * 4 + 256);
    const float4 b0 = *reinterpret_cast<const float4*>(b + lane * 4);
    const float4 b1 = *reinterpret_cast<const float4*>(b + lane * 4 + 256);
    float ov[8];
    ov[0] = fmaf(dx[0] * inv, g0.x, b0.x); ov[1] = fmaf(dx[1] * inv, g0.y, b0.y);
    ov[2] = fmaf(dx[2] * inv, g0.z, b0.z); ov[3] = fmaf(dx[3] * inv, g0.w, b0.w);
    ov[4] = fmaf(dx[4] * inv, g1.x, b1.x); ov[5] = fmaf(dx[5] * inv, g1.y, b1.y);
    ov[6] = fmaf(dx[6] * inv, g1.z, b1.z); ov[7] = fmaf(dx[7] * inv, g1.w, b1.w);

    U16x4 h0, l0, h1, l1;
    splitbf(ov[0], h0.x, l0.x); splitbf(ov[1], h0.y, l0.y);
    splitbf(ov[2], h0.z, l0.z); splitbf(ov[3], h0.w, l0.w);
    splitbf(ov[4], h1.x, l1.x); splitbf(ov[5], h1.y, l1.y);
    splitbf(ov[6], h1.z, l1.z); splitbf(ov[7], h1.w, l1.w);
    const size_t o = (size_t)row * EMB + lane * 4;
    *reinterpret_cast<U16x4*>(hhi + o)       = h0;
    *reinterpret_cast<U16x4*>(hhi + o + 256) = h1;
    *reinterpret_cast<U16x4*>(hlo + o)       = l0;
    *reinterpret_cast<U16x4*>(hlo + o + 256) = l1;
}

// ---------------------------------------------------------------- split-bf16 MFMA GEMM
// A (hi/lo bf16) [M=4096][K] row-major; Bt (hi/lo bf16) [N][K] row-major.
// Double-buffered LDS (1 barrier/K-step), XOR-swizzled LDS layout
// (pre-swizzled global source, rule #21), XCD-aware bijective block swizzle.
enum { EPI_QKV = 0, EPI_RES = 1, EPI_RELU_SPLIT = 2, EPI_OUT = 3 };

template<int WMC, int EPI>
__global__ __launch_bounds__(256)
void gemm_mfma(const u16* __restrict__ Ah, const u16* __restrict__ Al,
               const u16* __restrict__ Bh, const u16* __restrict__ Bl,
               const float* __restrict__ bias, int K, int N,
               float* o0,
               u16* __restrict__ u0, u16* __restrict__ u1, u16* __restrict__ u2)
{
    constexpr int BM = WMC * 64;
    constexpr int NFRAG = (WMC == 2) ? 4 : 2;
    constexpr int WSP = 16 * NFRAG;                 // per-wave n-span

    __shared__ __align__(16) u16 AhS[2][BM * 32], AlS[2][BM * 32];
    __shared__ __align__(16) u16 BhS[2][128 * 32], BlS[2][128 * 32];

    const int tid  = threadIdx.x;
    const int lane = tid & 63, w = tid >> 6;
    const int wm = (WMC == 2) ? (w >> 1) : 0;
    const int wn = (WMC == 2) ? (w & 1) : w;

    // XCD-aware bijective swizzle (all grids have nwg % 8 == 0), column-major
    // chunked so each XCD owns a contiguous run of B-panels (L2-resident).
    const int gy = (int)gridDim.y;
    int bid = (int)blockIdx.x * gy + (int)blockIdx.y;
    const int cpx = ((int)gridDim.x * gy) >> 3;
    bid = (bid & 7) * cpx + (bid >> 3);
    const int m0 = (bid % gy) * BM, n0 = (bid / gy) * 128;

    v4f acc[4][NFRAG];
    #pragma unroll
    for (int mi = 0; mi < 4; ++mi)
        #pragma unroll
        for (int ni = 0; ni < NFRAG; ++ni) acc[mi][ni] = (v4f)0.f;

    const int arow = lane & 15, kgi = lane >> 4;

    // stage K-slab k0 into LDS buffer buf. LDS dest is linear (chunk order);
    // global source column-group is XOR-swizzled: L[r][cg] = G[r][cg^((r>>1)&3)]
    auto stage = [&](int buf, int k0) {
        #pragma unroll
        for (int u = 0; u < WMC; ++u) {
            const int ch = u * 256 + tid;
            const int r = ch >> 2, cg = ch & 3;
            const int sc8 = (cg ^ ((r >> 1) & 3)) * 8;
            const size_t go = (size_t)(m0 + r) * K + k0 + sc8;
            __builtin_amdgcn_global_load_lds((gas_t)(Ah + go), (las_t)(&AhS[buf][ch * 8]), 16, 0, 0);
            __builtin_amdgcn_global_load_lds((gas_t)(Al + go), (las_t)(&AlS[buf][ch * 8]), 16, 0, 0);
        }
        #pragma unroll
        for (int u = 0; u < 2; ++u) {
            const int ch = u * 256 + tid;
            const int r = ch >> 2, cg = ch & 3;
            const int sc8 = (cg ^ ((r >> 1) & 3)) * 8;
            const size_t go = (size_t)(n0 + r) * K + k0 + sc8;
            __builtin_amdgcn_global_load_lds((gas_t)(Bh + go), (las_t)(&BhS[buf][ch * 8]), 16, 0, 0);
            __builtin_amdgcn_global_load_lds((gas_t)(Bl + go), (las_t)(&BlS[buf][ch * 8]), 16, 0, 0);
        }
    };

    stage(0, 0);
    const int NK = K >> 5;
    for (int ks = 0; ks < NK; ++ks) {
        const int cur = ks & 1;
        __syncthreads();                       // staged(cur) done; prior reads of cur^1 done
        if (ks + 1 < NK) stage(cur ^ 1, (ks + 1) * 32);

        v8s ah[4], al[4], bh[NFRAG], bl[NFRAG];
        #pragma unroll
        for (int mi = 0; mi < 4; ++mi) {
            const int ar = wm * 64 + mi * 16 + arow;
            const int idx = ar * 32 + (kgi ^ ((ar >> 1) & 3)) * 8;
            ah[mi] = *reinterpret_cast<const v8s*>(&AhS[cur][idx]);
            al[mi] = *reinterpret_cast<const v8s*>(&AlS[cur][idx]);
        }
        #pragma unroll
        for (int ni = 0; ni < NFRAG; ++ni) {
            const int br = wn * WSP + ni * 16 + arow;
            const int idx = br * 32 + (kgi ^ ((br >> 1) & 3)) * 8;
            bh[ni] = *reinterpret_cast<const v8s*>(&BhS[cur][idx]);
            bl[ni] = *reinterpret_cast<const v8s*>(&BlS[cur][idx]);
        }
        #pragma unroll
        for (int mi = 0; mi < 4; ++mi)
            #pragma unroll
            for (int ni = 0; ni < NFRAG; ++ni) {
                acc[mi][ni] = __builtin_amdgcn_mfma_f32_16x16x32_bf16(ah[mi], bh[ni], acc[mi][ni], 0, 0, 0);
                acc[mi][ni] = __builtin_amdgcn_mfma_f32_16x16x32_bf16(ah[mi], bl[ni], acc[mi][ni], 0, 0, 0);
                acc[mi][ni] = __builtin_amdgcn_mfma_f32_16x16x32_bf16(al[mi], bh[ni], acc[mi][ni], 0, 0, 0);
            }
    }

    // epilogue: C/D layout row=(lane>>4)*4+j, col=lane&15
    const int crow0 = (lane >> 4) * 4;
    const int ccol  = lane & 15;
    #pragma unroll
    for (int mi = 0; mi < 4; ++mi) {
        const int mbase = m0 + wm * 64 + mi * 16 + crow0;
        #pragma unroll
        for (int ni = 0; ni < NFRAG; ++ni) {
            const int n = n0 + wn * WSP + ni * 16 + ccol;
            if constexpr (EPI == EPI_QKV) {
                // q: bf16*SM_SCALE [B,H,T,D]; k: bf16 [B,H,T,D]; v: bf16 [B,H,D,T]
                const int sel = n >> 9, hh = (n >> 6) & 7, dd = n & 63;
                const int bbb = mbase >> 11, t = mbase & (SEQ - 1);
                if (sel == 2) {
                    U16x4 pv;
                    pv.x = f2bf(acc[mi][ni][0]); pv.y = f2bf(acc[mi][ni][1]);
                    pv.z = f2bf(acc[mi][ni][2]); pv.w = f2bf(acc[mi][ni][3]);
                    *reinterpret_cast<U16x4*>(
                        u2 + ((size_t)((bbb * NH + hh) * HDIM + dd) * SEQ + t)) = pv;
                } else {
                    u16* dst = sel ? u1 : u0;
                    const float scl = sel ? 1.0f : SM_SCALE;
                    #pragma unroll
                    for (int j = 0; j < 4; ++j) {
                        const int m = mbase + j;
                        dst[((size_t)((m >> 11) * NH + hh) * SEQ + (m & (SEQ - 1))) * HDIM + dd]
                            = f2bf(acc[mi][ni][j] * scl);
                    }
                }
            } else if constexpr (EPI == EPI_RES) {
                const float bv = bias[n];
                #pragma unroll
                for (int j = 0; j < 4; ++j) {
                    const size_t o = (size_t)(mbase + j) * N + n;
                    o0[o] = o0[o] + acc[mi][ni][j] + bv;
                }
            } else if constexpr (EPI == EPI_RELU_SPLIT) {
                const float bv = bias[n];
                #pragma unroll
                for (int j = 0; j < 4; ++j) {
                    const float v_ = fmaxf(acc[mi][ni][j] + bv, 0.f);
                    u16 hi, lo; splitbf(v_, hi, lo);
                    const size_t o = (size_t)(mbase + j) * N + n;
                    u0[o] = hi; u1[o] = lo;
                }
            } else {                                    // EPI_OUT (LM head, ragged N)
                if (n < N) {
                    const float bv = bias[n];
                    #pragma unroll
                    for (int j = 0; j < 4; ++j)
                        o0[(size_t)(mbase + j) * N + n] = acc[mi][ni][j] + bv;
                }
            }
        }
    }
}

// ---------------------------------------------------------------- MFMA flash attention
// 2 waves x 32 q rows = 64 q/block; grid (32 qt, 16 bh). bf16 Q(pre-scaled)/K/V.
// S^T = K*Q^T (per-lane softmax state); P via per-wave swizzled LDS; O^T = V^T*P^T.
// qt direction alternates with bh-half so co-resident block pairs are complementary.
__global__ __launch_bounds__(128)
void attn_mfma(const u16* __restrict__ qg, const u16* __restrict__ kg,
               const u16* __restrict__ vg, u16* __restrict__ ohi,
               u16* __restrict__ olo)
{
    __shared__ __align__(16) u16 KT[2][4096];   // swizzled [kv 64][d 64]
    __shared__ __align__(16) u16 VT[2][4096];   // swizzled [d 64][kv 64]
    __shared__ __align__(16) u16 PL[2][2048];   // per-wave, swizzled [q 32][kv 64]

    const int tid = threadIdx.x, lane = tid & 63, w = tid >> 6;
    const int g = lane >> 4, c = lane & 15;
    const int bh = blockIdx.y;
    const int qt = (bh & 8) ? (int)blockIdx.x : 31 - (int)blockIdx.x;  // load balance
    const int bb = bh >> 3, hh = bh & 7;

    const u16* qb = qg + (size_t)bh * (SEQ * HDIM);
    const u16* kb = kg + (size_t)bh * (SEQ * HDIM);
    const u16* vb = vg + (size_t)bh * (HDIM * SEQ);

    // staging chunk constants: chunk = w*256 + i*64 + lane; row=chunk>>3,
    // source slot pre-swizzled so LDS (linear dest) holds XOR-swizzled layout
    int soffK[4], soffV[4];
    #pragma unroll
    for (int i = 0; i < 4; ++i) {
        const int ch = w * 256 + i * 64 + lane;
        const int r = ch >> 3;
        const int sc_ = ((ch & 7) ^ (r & 7)) * 8;
        soffK[i] = r * HDIM + sc_;          // + kt*64*HDIM per iter
        soffV[i] = r * SEQ + sc_;           // + kt*64 per iter
    }

    // Q fragments (B-operand): lane holds Q[q=nf*16+c][d=ch*32+g*8 ..+7]
    v8s qreg[2][2];
    const int q0 = qt * 64 + w * 32;
    #pragma unroll
    for (int nf = 0; nf < 2; ++nf)
        #pragma unroll
        for (int ch = 0; ch < 2; ++ch)
            qreg[nf][ch] = *reinterpret_cast<const v8s*>(
                qb + (size_t)(q0 + nf * 16 + c) * HDIM + ch * 32 + g * 8);

    v4f oacc[4][2];
    #pragma unroll
    for (int mf = 0; mf < 4; ++mf)
        #pragma unroll
        for (int nf = 0; nf < 2; ++nf) oacc[mf][nf] = (v4f)0.f;
    float m_[2] = {-3.0e38f, -3.0e38f}, l_[2] = {0.f, 0.f};

    // prologue: stage kt=0 into buf 0
    #pragma unroll
    for (int i = 0; i < 4; ++i) {
        const int ch = w * 256 + i * 64 + lane;
        __builtin_amdgcn_global_load_lds((gas_t)(kb + soffK[i]), (las_t)(&KT[0][ch * 8]), 16, 0, 0);
        __builtin_amdgcn_global_load_lds((gas_t)(vb + soffV[i]), (las_t)(&VT[0][ch * 8]), 16, 0, 0);
    }
    __syncthreads();

    for (int kt = 0; kt <= qt; ++kt) {
        const int cur = kt & 1;
        if (kt < qt) {       // async-stage next tile into other buffer
            const int kn = kt + 1;
            #pragma unroll
            for (int i = 0; i < 4; ++i) {
                const int ch = w * 256 + i * 64 + lane;
                __builtin_amdgcn_global_load_lds((gas_t)(kb + (size_t)kn * 64 * HDIM + soffK[i]),
                                                 (las_t)(&KT[cur ^ 1][ch * 8]), 16, 0, 0);
                __builtin_amdgcn_global_load_lds((gas_t)(vb + (size_t)kn * 64 + soffV[i]),
                                                 (las_t)(&VT[cur ^ 1][ch * 8]), 16, 0, 0);
            }
        }

        // ---- S^T = K * Q^T ----
        v4f sacc[4][2];
        #pragma unroll
        for (int mf = 0; mf < 4; ++mf)
            #pragma unroll
            for (int nf = 0; nf < 2; ++nf) sacc[mf][nf] = (v4f)0.f;
        #pragma unroll
        for (int ch = 0; ch < 2; ++ch) {
            v8s kf[4];
            #pragma unroll
            for (int mf = 0; mf < 4; ++mf) {
                const int row = mf * 16 + c;
                int idx = row * 64 + ch * 32 + g * 8;
                idx ^= (row & 7) << 3;
                kf[mf] = *reinterpret_cast<const v8s*>(&KT[cur][idx]);
            }
            #pragma unroll
            for (int mf = 0; mf < 4; ++mf)
                #pragma unroll
                for (int nf = 0; nf < 2; ++nf)
                    sacc[mf][nf] = __builtin_amdgcn_mfma_f32_16x16x32_bf16(
                        kf[mf], qreg[nf][ch], sacc[mf][nf], 0, 0, 0);
        }

        // causal mask on diagonal tile
        if (kt == qt) {
            #pragma unroll
            for (int mf = 0; mf < 4; ++mf)
                #pragma unroll
                for (int nf = 0; nf < 2; ++nf)
                    #pragma unroll
                    for (int j = 0; j < 4; ++j) {
                        const int kvl = mf * 16 + g * 4 + j;
                        const int ql  = w * 32 + nf * 16 + c;
                        if (kvl > ql) sacc[mf][nf][j] = -3.0e38f;
                    }
        }

        // ---- online softmax (per-lane per nf) + P -> swizzled LDS ----
        #pragma unroll
        for (int nf = 0; nf < 2; ++nf) {
            float pmax = -3.0e38f;
            #pragma unroll
            for (int mf = 0; mf < 4; ++mf)
                #pragma unroll
                for (int j = 0; j < 4; ++j) pmax = fmaxf(pmax, sacc[mf][nf][j]);
            pmax = fmaxf(pmax, __shfl_xor(pmax, 16));
            pmax = fmaxf(pmax, __shfl_xor(pmax, 32));
            const float mnew = fmaxf(m_[nf], pmax);
            const float sc = __expf(m_[nf] - mnew);
            m_[nf] = mnew;
            float rs = 0.f;
            #pragma unroll
            for (int mf = 0; mf < 4; ++mf) {
                float p0 = __expf(sacc[mf][nf][0] - mnew);
                float p1 = __expf(sacc[mf][nf][1] - mnew);
                float p2 = __expf(sacc[mf][nf][2] - mnew);
                float p3 = __expf(sacc[mf][nf][3] - mnew);
                rs += (p0 + p1) + (p2 + p3);
                const u32 w0 = (u32)f2bf(p0) | ((u32)f2bf(p1) << 16);
                const u32 w1 = (u32)f2bf(p2) | ((u32)f2bf(p3) << 16);
                const int qrow = nf * 16 + c;                // 0..31
                int idx0 = qrow * 64 + mf * 16 + g * 4;      // kv even
                idx0 ^= (qrow & 7) << 3;
                *reinterpret_cast<u32*>(&PL[w][idx0]) = w0;
                int idx1 = qrow * 64 + mf * 16 + g * 4 + 2;
                idx1 ^= (qrow & 7) << 3;
                *reinterpret_cast<u32*>(&PL[w][idx1]) = w1;
            }
            rs += __shfl_xor(rs, 16);
            rs += __shfl_xor(rs, 32);
            l_[nf] = l_[nf] * sc + rs;
            #pragma unroll
            for (int mf = 0; mf < 4; ++mf)
                #pragma unroll
                for (int j = 0; j < 4; ++j) oacc[mf][nf][j] *= sc;
        }

        // ---- O^T += V^T * P^T ----
        #pragma unroll
        for (int ch = 0; ch < 2; ++ch) {
            v8s vf[4], pf[2];
            #pragma unroll
            for (int mf = 0; mf < 4; ++mf) {
                const int row = mf * 16 + c;                 // d row
                int idx = row * 64 + ch * 32 + g * 8;
                idx ^= (row & 7) << 3;
                vf[mf] = *reinterpret_cast<const v8s*>(&VT[cur][idx]);
            }
            #pragma unroll
            for (int nf = 0; nf < 2; ++nf) {
                const int qrow = nf * 16 + c;
                int idx = qrow * 64 + ch * 32 + g * 8;
                idx ^= (qrow & 7) << 3;
                pf[nf] = *reinterpret_cast<const v8s*>(&PL[w][idx]);
            }
            #pragma unroll
            for (int mf = 0; mf < 4; ++mf)
                #pragma unroll
                for (int nf = 0; nf < 2; ++nf)
                    oacc[mf][nf] = __builtin_amdgcn_mfma_f32_16x16x32_bf16(
                        vf[mf], pf[nf], oacc[mf][nf], 0, 0, 0);
        }
        __syncthreads();   // drains vmcnt (next tile staged) + protects buffers
    }

    // epilogue: O^T element (d = mf*16+g*4+j, q = nf*16+c); write hi/lo bf16
    #pragma unroll
    for (int nf = 0; nf < 2; ++nf) {
        const float inv = 1.0f / l_[nf];
        const size_t row = (size_t)bb * SEQ + q0 + nf * 16 + c;   // token
        #pragma unroll
        for (int mf = 0; mf < 4; ++mf) {
            float v0 = oacc[mf][nf][0] * inv, v1 = oacc[mf][nf][1] * inv;
            float v2 = oacc[mf][nf][2] * inv, v3 = oacc[mf][nf][3] * inv;
            U16x4 hv, lv;
            splitbf(v0, hv.x, lv.x); splitbf(v1, hv.y, lv.y);
            splitbf(v2, hv.z, lv.z); splitbf(v3, hv.w, lv.w);
            const size_t off = row * EMB + hh * HDIM + mf * 16 + g * 4;
            *reinterpret_cast<U16x4*>(ohi + off) = hv;
            *reinterpret_cast<U16x4*>(olo + off) = lv;
        }
    }
}

// ---------------------------------------------------------------- launch
extern "C" void kernel_launch(void* const* d_in, const int* in_sizes, int n_in,
                              void* d_out, int out_size, void* d_ws, size_t ws_size,
                              hipStream_t stream)
{
    const int*   tokens  = (const int*)  d_in[0];
    const float* tok_emb = (const float*)d_in[1];
    const float* pos_emb = (const float*)d_in[2];
    const float* Wq      = (const float*)d_in[3];
    const float* Wk      = (const float*)d_in[4];
    const float* Wv      = (const float*)d_in[5];
    const float* Wo      = (const float*)d_in[6];
    const float* bo      = (const float*)d_in[7];
    const float* ln1_g   = (const float*)d_in[8];
    const float* ln1_b   = (const float*)d_in[9];
    const float* ln2_g   = (const float*)d_in[10];
    const float* ln2_b   = (const float*)d_in[11];
    const float* W1      = (const float*)d_in[12];
    const float* b1      = (const float*)d_in[13];
    const float* W2      = (const float*)d_in[14];
    const float* b2      = (const float*)d_in[15];
    const float* lnf_g   = (const float*)d_in[16];
    const float* lnf_b   = (const float*)d_in[17];
    const float* Wlm     = (const float*)d_in[18];
    const float* blm     = (const float*)d_in[19];
    float* out = (float*)d_out;

    // workspace: x fp32 (8MB) | 32MB region {q,k,v,ohi,olo bf16 (20MB)} aliased
    // by {ff hi/lo bf16 (32MB)} | h hi/lo (8MB) | transposed split weights (~67MB)
    const size_t NE = (size_t)NTOK * EMB;            // 2097152
    const size_t NF = (size_t)NTOK * FFD;            // 8388608
    float* x   = (float*)d_ws;
    float* zr  = x + NE;
    u16* qb16  = (u16*)zr;
    u16* kb16  = qb16 + NE;
    u16* vb16  = kb16 + NE;                          // [B,H,D,T]
    u16* ohi   = vb16 + NE;
    u16* olo   = ohi + NE;
    u16* ffhi  = (u16*)zr;                           // aliases q..olo (disjoint lifetime)
    u16* fflo  = ffhi + NF;
    u16* hhi   = (u16*)(zr + 4 * NE);
    u16* hlo   = hhi + NE;

    const size_t SQKV = (size_t)4 * 1536 * 512;
    const size_t SWO  = (size_t)4 * 512 * 512;
    const size_t SW1  = (size_t)4 * 2048 * 512;
    const size_t SLM  = (size_t)8064 * 512;
    u16* qkvT_h = hlo + NE;        u16* qkvT_l = qkvT_h + SQKV;
    u16* woT_h  = qkvT_l + SQKV;   u16* woT_l  = woT_h + SWO;
    u16* w1T_h  = woT_l + SWO;     u16* w1T_l  = w1T_h + SW1;
    u16* w2T_h  = w1T_l + SW1;     u16* w2T_l  = w2T_h + SW1;
    u16* wlmT_h = w2T_l + SW1;     u16* wlmT_l = wlmT_h + SLM;

    // ---- weight prep (every call) ----
    transpose_qkv<<<dim3(2, 16, 96), 256, 0, stream>>>(Wq, Wk, Wv, qkvT_h, qkvT_l);
    transpose_split<<<dim3(16, 16, 4), 256, 0, stream>>>(Wo, woT_h, woT_l, 512, 512,
                                                         262144, 262144);
    transpose_split<<<dim3(64, 16, 4), 256, 0, stream>>>(W1, w1T_h, w1T_l, 512, 2048,
                                                         1048576, 1048576);
    transpose_split<<<dim3(16, 64, 4), 256, 0, stream>>>(W2, w2T_h, w2T_l, 2048, 512,
                                                         1048576, 1048576);
    transpose_split<<<dim3(252, 16, 1), 256, 0, stream>>>(Wlm, wlmT_h, wlmT_l, 512, 8000,
                                                          0, 0);

    embed_kernel<<<NTOK, 128, 0, stream>>>(tokens, tok_emb, pos_emb, x);

    for (int l = 0; l < 4; ++l) {
        ln_split_kernel<<<NTOK / 4, 256, 0, stream>>>(x, ln1_g + l * EMB, ln1_b + l * EMB,
                                                      hhi, hlo);
        gemm_mfma<2, EPI_QKV><<<dim3(12, 32), 256, 0, stream>>>(
            hhi, hlo, qkvT_h + (size_t)l * 1536 * 512, qkvT_l + (size_t)l * 1536 * 512,
            nullptr, EMB, 1536, nullptr, qb16, kb16, vb16);

        attn_mfma<<<dim3(32, 16), 128, 0, stream>>>(qb16, kb16, vb16, ohi, olo);

        gemm_mfma<1, EPI_RES><<<dim3(4, 64), 256, 0, stream>>>(
            ohi, olo, woT_h + (size_t)l * 262144, woT_l + (size_t)l * 262144,
            bo + l * EMB, EMB, EMB, x, nullptr, nullptr, nullptr);

        ln_split_kernel<<<NTOK / 4, 256, 0, stream>>>(x, ln2_g + l * EMB, ln2_b + l * EMB,
                                                      hhi, hlo);
        gemm_mfma<2, EPI_RELU_SPLIT><<<dim3(16, 32), 256, 0, stream>>>(
            hhi, hlo, w1T_h + (size_t)l * 1048576, w1T_l + (size_t)l * 1048576,
            b1 + l * FFD, EMB, FFD, nullptr, ffhi, fflo, nullptr);

        gemm_mfma<1, EPI_RES><<<dim3(4, 64), 256, 0, stream>>>(
            ffhi, fflo, w2T_h + (size_t)l * 1048576, w2T_l + (size_t)l * 1048576,
            b2 + l * EMB, FFD, EMB, x, nullptr, nullptr, nullptr);
    }

    ln_split_kernel<<<NTOK / 4, 256, 0, stream>>>(x, lnf_g, lnf_b, hhi, hlo);

    gemm_mfma<2, EPI_OUT><<<dim3(63, 32), 256, 0, stream>>>(
        hhi, hlo, wlmT_h, wlmT_l, blm, EMB, VOCAB, out, nullptr, nullptr, nullptr);
}

// Round 7
// 1084.706 us; speedup vs baseline: 1.9226x; 1.0959x over previous
//
#include <hip/hip_runtime.h>
#include <hip/hip_bf16.h>

#define NH 8
#define EMB 512
#define HDIM 64
#define SEQ 2048
#define VOCAB 8000
#define NTOK 4096
#define FFD 2048
#define LN_EPS 1e-5f
#define SM_SCALE 0.04419417382415922f   // 512^-0.5 (reference scales by E, not DH)

typedef unsigned short u16;
typedef unsigned int u32;
typedef short v8s __attribute__((ext_vector_type(8)));   // 8 bf16 in 4 VGPRs
typedef float v4f __attribute__((ext_vector_type(4)));   // MFMA accumulator

typedef const __attribute__((address_space(1))) void* gas_t;
typedef __attribute__((address_space(3))) void* las_t;

struct __align__(8) U16x4 { u16 x, y, z, w; };

__device__ __forceinline__ u16 f2bf(float x) {
    union { float f; unsigned int u; } c; c.f = x;
    return (u16)((c.u + 0x7FFFu + ((c.u >> 16) & 1u)) >> 16);   // RNE
}
__device__ __forceinline__ float bf2f(u16 b) {
    union { unsigned int u; float f; } c; c.u = ((unsigned int)b) << 16; return c.f;
}
__device__ __forceinline__ void splitbf(float x, u16& hi, u16& lo) {
    hi = f2bf(x);
    lo = f2bf(x - bf2f(hi));
}

// ---------------------------------------------------------------- embed
__global__ __launch_bounds__(128)
void embed_kernel(const int* __restrict__ tokens, const float* __restrict__ tok_emb,
                  const float* __restrict__ pos_emb, float* __restrict__ x)
{
    const int row = blockIdx.x;            // b*SEQ + t
    const int t   = row & (SEQ - 1);
    const int tok = tokens[row];
    const int c   = threadIdx.x * 4;
    const float4 a = *reinterpret_cast<const float4*>(tok_emb + (size_t)tok * EMB + c);
    const float4 p = *reinterpret_cast<const float4*>(pos_emb + (size_t)t * EMB + c);
    float4 r; r.x = a.x + p.x; r.y = a.y + p.y; r.z = a.z + p.z; r.w = a.w + p.w;
    *reinterpret_cast<float4*>(x + (size_t)row * EMB + c) = r;
}

// ---------------------------------------------------------------- merged weight prep
// All five transpose+split jobs in ONE dispatch (one 32x32 tile per block).
// src fp32 [R-dim rows][C-dim cols]; dst bf16 hi/lo [C(padded)][R].
__global__ __launch_bounds__(256)
void prep_weights(const float* __restrict__ Wq, const float* __restrict__ Wk,
                  const float* __restrict__ Wv, const float* __restrict__ Wo,
                  const float* __restrict__ W1, const float* __restrict__ W2,
                  const float* __restrict__ Wlm,
                  u16* __restrict__ qkvT_h, u16* __restrict__ qkvT_l,
                  u16* __restrict__ woT_h,  u16* __restrict__ woT_l,
                  u16* __restrict__ w1T_h,  u16* __restrict__ w1T_l,
                  u16* __restrict__ w2T_h,  u16* __restrict__ w2T_l,
                  u16* __restrict__ wlmT_h, u16* __restrict__ wlmT_l)
{
    const int t = blockIdx.x;
    const float* src; u16 *dh, *dl; int R, C, ct, rt;
    if (t < 3072) {                                  // QKV: 96 z * (2 x * 16 y)
        const int z = t >> 5, rem = t & 31;
        const int l = z / 24, r2 = z % 24, sel = r2 >> 3, h = r2 & 7;
        src = (sel == 0 ? Wq : sel == 1 ? Wk : Wv) + (size_t)(l * 8 + h) * EMB * HDIM;
        const size_t dbase = ((size_t)l * 1536 + sel * 512 + h * 64) * EMB;
        dh = qkvT_h + dbase; dl = qkvT_l + dbase;
        R = EMB; C = HDIM; ct = (rem & 1) * 32; rt = (rem >> 1) * 32;
    } else if (t < 4096) {                           // Wo: 4 z * (16 x * 16 y)
        const int t2 = t - 3072, z = t2 >> 8, rem = t2 & 255;
        src = Wo + (size_t)z * 262144;
        dh = woT_h + (size_t)z * 262144; dl = woT_l + (size_t)z * 262144;
        R = 512; C = 512; ct = (rem & 15) * 32; rt = (rem >> 4) * 32;
    } else if (t < 8192) {                           // W1: 4 z * (64 x * 16 y)
        const int t3 = t - 4096, z = t3 >> 10, rem = t3 & 1023;
        src = W1 + (size_t)z * 1048576;
        dh = w1T_h + (size_t)z * 1048576; dl = w1T_l + (size_t)z * 1048576;
        R = 512; C = 2048; ct = (rem & 63) * 32; rt = (rem >> 6) * 32;
    } else if (t < 12288) {                          // W2: 4 z * (16 x * 64 y)
        const int t4 = t - 8192, z = t4 >> 10, rem = t4 & 1023;
        src = W2 + (size_t)z * 1048576;
        dh = w2T_h + (size_t)z * 1048576; dl = w2T_l + (size_t)z * 1048576;
        R = 2048; C = 512; ct = (rem & 15) * 32; rt = (rem >> 4) * 32;
    } else {                                         // Wlm: 252 x * 16 y
        const int t5 = t - 12288;
        src = Wlm; dh = wlmT_h; dl = wlmT_l;
        R = 512; C = 8000; ct = (t5 % 252) * 32; rt = (t5 / 252) * 32;
    }

    __shared__ float sh[32][33];
    const int cx = threadIdx.x & 31, ry = threadIdx.x >> 5;
    #pragma unroll
    for (int i = 0; i < 4; ++i) {
        const int r = ry + i * 8;
        float v = 0.f;
        if (ct + cx < C) v = src[(size_t)(rt + r) * C + ct + cx];
        sh[r][cx] = v;
    }
    __syncthreads();
    #pragma unroll
    for (int i = 0; i < 4; ++i) {
        const int r = ry + i * 8;
        u16 hi, lo; splitbf(sh[cx][r], hi, lo);
        const size_t o = (size_t)(ct + r) * R + rt + cx;
        dh[o] = hi; dl[o] = lo;
    }
}

// ---------------------------------------------------------------- layernorm -> bf16 hi/lo
__global__ __launch_bounds__(256)
void ln_split_kernel(const float* __restrict__ x, const float* __restrict__ g,
                     const float* __restrict__ b, u16* __restrict__ hhi,
                     u16* __restrict__ hlo)
{
    const int row  = blockIdx.x * 4 + (threadIdx.x >> 6);
    const int lane = threadIdx.x & 63;
    const float* xp = x + (size_t)row * EMB;
    const float4 v0 = *reinterpret_cast<const float4*>(xp + lane * 4);
    const float4 v1 = *reinterpret_cast<const float4*>(xp + lane * 4 + 256);

    float s = v0.x + v0.y + v0.z + v0.w + v1.x + v1.y + v1.z + v1.w;
    #pragma unroll
    for (int off = 32; off > 0; off >>= 1) s += __shfl_xor(s, off);
    const float mean = s * (1.0f / EMB);

    float dx[8] = {v0.x - mean, v0.y - mean, v0.z - mean, v0.w - mean,
                   v1.x - mean, v1.y - mean, v1.z - mean, v1.w - mean};
    float vs = 0.f;
    #pragma unroll
    for (int u = 0; u < 8; ++u) vs = fmaf(dx[u], dx[u], vs);
    #pragma unroll
    for (int off = 32; off > 0; off >>= 1) vs += __shfl_xor(vs, off);
    const float inv = 1.0f / sqrtf(vs * (1.0f / EMB) + LN_EPS);

    const float4 g0 = *reinterpret_cast<const float4*>(g + lane * 4);
    const float4 g1 = *reinterpret_cast<const float4*>(g + lane * 4 + 256);
    const float4 b0 = *reinterpret_cast<const float4*>(b + lane * 4);
    const float4 b1 = *reinterpret_cast<const float4*>(b + lane * 4 + 256);
    float ov[8];
    ov[0] = fmaf(dx[0] * inv, g0.x, b0.x); ov[1] = fmaf(dx[1] * inv, g0.y, b0.y);
    ov[2] = fmaf(dx[2] * inv, g0.z, b0.z); ov[3] = fmaf(dx[3] * inv, g0.w, b0.w);
    ov[4] = fmaf(dx[4] * inv, g1.x, b1.x); ov[5] = fmaf(dx[5] * inv, g1.y, b1.y);
    ov[6] = fmaf(dx[6] * inv, g1.z, b1.z); ov[7] = fmaf(dx[7] * inv, g1.w, b1.w);

    U16x4 h0, l0, h1, l1;
    splitbf(ov[0], h0.x, l0.x); splitbf(ov[1], h0.y, l0.y);
    splitbf(ov[2], h0.z, l0.z); splitbf(ov[3], h0.w, l0.w);
    splitbf(ov[4], h1.x, l1.x); splitbf(ov[5], h1.y, l1.y);
    splitbf(ov[6], h1.z, l1.z); splitbf(ov[7], h1.w, l1.w);
    const size_t o = (size_t)row * EMB + lane * 4;
    *reinterpret_cast<U16x4*>(hhi + o)       = h0;
    *reinterpret_cast<U16x4*>(hhi + o + 256) = h1;
    *reinterpret_cast<U16x4*>(hlo + o)       = l0;
    *reinterpret_cast<U16x4*>(hlo + o + 256) = l1;
}

// ---------------------------------------------------------------- split-bf16 MFMA GEMM
// A (hi/lo bf16) [M=4096][K] row-major; Bt (hi/lo bf16) [N][K] row-major.
// WMC=2: 128x128 tile (2x2 waves, 4x4 frags). WMC=0: 64x64 tile (2x2 waves, 2x2 frags).
// Double-buffered LDS (1 barrier/K-step), XOR-swizzled LDS (pre-swizzled global
// source, rule #21), XCD-aware bijective block swizzle.
enum { EPI_QKV = 0, EPI_RES = 1, EPI_RELU_SPLIT = 2, EPI_OUT = 3 };

template<int WMC, int EPI>
__global__ __launch_bounds__(256)
void gemm_mfma(const u16* __restrict__ Ah, const u16* __restrict__ Al,
               const u16* __restrict__ Bh, const u16* __restrict__ Bl,
               const float* __restrict__ bias, int K, int N,
               float* o0,
               u16* __restrict__ u0, u16* __restrict__ u1, u16* __restrict__ u2)
{
    constexpr int BM = (WMC == 2) ? 128 : 64;
    constexpr int BN = (WMC == 0) ? 64 : 128;
    constexpr int MFRAG = (WMC == 0) ? 2 : 4;
    constexpr int NFRAG = (WMC == 2) ? 4 : 2;

    __shared__ __align__(16) u16 AhS[2][BM * 32], AlS[2][BM * 32];
    __shared__ __align__(16) u16 BhS[2][BN * 32], BlS[2][BN * 32];

    const int tid  = threadIdx.x;
    const int lane = tid & 63, w = tid >> 6;
    int moff, noff;
    if constexpr (WMC == 2)      { moff = (w >> 1) * 64; noff = (w & 1) * 64; }
    else if constexpr (WMC == 1) { moff = 0;             noff = w * 32;       }
    else                         { moff = (w >> 1) * 32; noff = (w & 1) * 32; }

    // XCD-aware bijective swizzle (all grids have nwg % 8 == 0), column-major
    // chunked so each XCD owns a contiguous run of B-panels (L2-resident).
    const int gy = (int)gridDim.y;
    int bid = (int)blockIdx.x * gy + (int)blockIdx.y;
    const int cpx = ((int)gridDim.x * gy) >> 3;
    bid = (bid & 7) * cpx + (bid >> 3);
    const int m0 = (bid % gy) * BM, n0 = (bid / gy) * BN;

    v4f acc[MFRAG][NFRAG];
    #pragma unroll
    for (int mi = 0; mi < MFRAG; ++mi)
        #pragma unroll
        for (int ni = 0; ni < NFRAG; ++ni) acc[mi][ni] = (v4f)0.f;

    const int arow = lane & 15, kgi = lane >> 4;

    // stage K-slab k0 into LDS buffer buf. LDS dest is linear (chunk order);
    // global source column-group is XOR-swizzled: L[r][cg] = G[r][cg^((r>>1)&3)]
    auto stage = [&](int buf, int k0) {
        #pragma unroll
        for (int u = 0; u < BM / 64; ++u) {
            const int ch = u * 256 + tid;
            const int r = ch >> 2, cg = ch & 3;
            const int sc8 = (cg ^ ((r >> 1) & 3)) * 8;
            const size_t go = (size_t)(m0 + r) * K + k0 + sc8;
            __builtin_amdgcn_global_load_lds((gas_t)(Ah + go), (las_t)(&AhS[buf][ch * 8]), 16, 0, 0);
            __builtin_amdgcn_global_load_lds((gas_t)(Al + go), (las_t)(&AlS[buf][ch * 8]), 16, 0, 0);
        }
        #pragma unroll
        for (int u = 0; u < BN / 64; ++u) {
            const int ch = u * 256 + tid;
            const int r = ch >> 2, cg = ch & 3;
            const int sc8 = (cg ^ ((r >> 1) & 3)) * 8;
            const size_t go = (size_t)(n0 + r) * K + k0 + sc8;
            __builtin_amdgcn_global_load_lds((gas_t)(Bh + go), (las_t)(&BhS[buf][ch * 8]), 16, 0, 0);
            __builtin_amdgcn_global_load_lds((gas_t)(Bl + go), (las_t)(&BlS[buf][ch * 8]), 16, 0, 0);
        }
    };

    stage(0, 0);
    const int NK = K >> 5;
    for (int ks = 0; ks < NK; ++ks) {
        const int cur = ks & 1;
        __syncthreads();                       // staged(cur) done; prior reads of cur^1 done
        if (ks + 1 < NK) stage(cur ^ 1, (ks + 1) * 32);

        v8s ah[MFRAG], al[MFRAG], bh[NFRAG], bl[NFRAG];
        #pragma unroll
        for (int mi = 0; mi < MFRAG; ++mi) {
            const int ar = moff + mi * 16 + arow;
            const int idx = ar * 32 + (kgi ^ ((ar >> 1) & 3)) * 8;
            ah[mi] = *reinterpret_cast<const v8s*>(&AhS[cur][idx]);
            al[mi] = *reinterpret_cast<const v8s*>(&AlS[cur][idx]);
        }
        #pragma unroll
        for (int ni = 0; ni < NFRAG; ++ni) {
            const int br = noff + ni * 16 + arow;
            const int idx = br * 32 + (kgi ^ ((br >> 1) & 3)) * 8;
            bh[ni] = *reinterpret_cast<const v8s*>(&BhS[cur][idx]);
            bl[ni] = *reinterpret_cast<const v8s*>(&BlS[cur][idx]);
        }
        #pragma unroll
        for (int mi = 0; mi < MFRAG; ++mi)
            #pragma unroll
            for (int ni = 0; ni < NFRAG; ++ni) {
                acc[mi][ni] = __builtin_amdgcn_mfma_f32_16x16x32_bf16(ah[mi], bh[ni], acc[mi][ni], 0, 0, 0);
                acc[mi][ni] = __builtin_amdgcn_mfma_f32_16x16x32_bf16(ah[mi], bl[ni], acc[mi][ni], 0, 0, 0);
                acc[mi][ni] = __builtin_amdgcn_mfma_f32_16x16x32_bf16(al[mi], bh[ni], acc[mi][ni], 0, 0, 0);
            }
    }

    // epilogue: C/D layout row=(lane>>4)*4+j, col=lane&15
    const int crow0 = (lane >> 4) * 4;
    const int ccol  = lane & 15;
    #pragma unroll
    for (int mi = 0; mi < MFRAG; ++mi) {
        const int mbase = m0 + moff + mi * 16 + crow0;
        #pragma unroll
        for (int ni = 0; ni < NFRAG; ++ni) {
            const int n = n0 + noff + ni * 16 + ccol;
            if constexpr (EPI == EPI_QKV) {
                // q: bf16*SM_SCALE [B,H,T,D]; k: bf16 [B,H,T,D]; v: bf16 [B,H,D,T]
                const int sel = n >> 9, hh = (n >> 6) & 7, dd = n & 63;
                const int bbb = mbase >> 11, t = mbase & (SEQ - 1);
                if (sel == 2) {
                    U16x4 pv;
                    pv.x = f2bf(acc[mi][ni][0]); pv.y = f2bf(acc[mi][ni][1]);
                    pv.z = f2bf(acc[mi][ni][2]); pv.w = f2bf(acc[mi][ni][3]);
                    *reinterpret_cast<U16x4*>(
                        u2 + ((size_t)((bbb * NH + hh) * HDIM + dd) * SEQ + t)) = pv;
                } else {
                    u16* dst = sel ? u1 : u0;
                    const float scl = sel ? 1.0f : SM_SCALE;
                    #pragma unroll
                    for (int j = 0; j < 4; ++j) {
                        const int m = mbase + j;
                        dst[((size_t)((m >> 11) * NH + hh) * SEQ + (m & (SEQ - 1))) * HDIM + dd]
                            = f2bf(acc[mi][ni][j] * scl);
                    }
                }
            } else if constexpr (EPI == EPI_RES) {
                const float bv = bias[n];
                #pragma unroll
                for (int j = 0; j < 4; ++j) {
                    const size_t o = (size_t)(mbase + j) * N + n;
                    o0[o] = o0[o] + acc[mi][ni][j] + bv;
                }
            } else if constexpr (EPI == EPI_RELU_SPLIT) {
                const float bv = bias[n];
                #pragma unroll
                for (int j = 0; j < 4; ++j) {
                    const float v_ = fmaxf(acc[mi][ni][j] + bv, 0.f);
                    u16 hi, lo; splitbf(v_, hi, lo);
                    const size_t o = (size_t)(mbase + j) * N + n;
                    u0[o] = hi; u1[o] = lo;
                }
            } else {                                    // EPI_OUT (LM head, ragged N)
                if (n < N) {
                    const float bv = bias[n];
                    #pragma unroll
                    for (int j = 0; j < 4; ++j)
                        o0[(size_t)(mbase + j) * N + n] = acc[mi][ni][j] + bv;
                }
            }
        }
    }
}

// ---------------------------------------------------------------- MFMA flash attention
// 2 waves x 32 q rows = 64 q/block; grid (32 qt, 16 bh). bf16 Q(pre-scaled)/K/V.
// S^T = K*Q^T (per-lane softmax state); P via per-wave swizzled LDS; O^T = V^T*P^T.
// qt direction alternates with bh-half so co-resident block pairs are complementary.
__global__ __launch_bounds__(128)
void attn_mfma(const u16* __restrict__ qg, const u16* __restrict__ kg,
               const u16* __restrict__ vg, u16* __restrict__ ohi,
               u16* __restrict__ olo)
{
    __shared__ __align__(16) u16 KT[2][4096];   // swizzled [kv 64][d 64]
    __shared__ __align__(16) u16 VT[2][4096];   // swizzled [d 64][kv 64]
    __shared__ __align__(16) u16 PL[2][2048];   // per-wave, swizzled [q 32][kv 64]

    const int tid = threadIdx.x, lane = tid & 63, w = tid >> 6;
    const int g = lane >> 4, c = lane & 15;
    const int bh = blockIdx.y;
    const int qt = (bh & 8) ? (int)blockIdx.x : 31 - (int)blockIdx.x;  // load balance
    const int bb = bh >> 3, hh = bh & 7;

    const u16* qb = qg + (size_t)bh * (SEQ * HDIM);
    const u16* kb = kg + (size_t)bh * (SEQ * HDIM);
    const u16* vb = vg + (size_t)bh * (HDIM * SEQ);

    // staging chunk constants: chunk = w*256 + i*64 + lane; row=chunk>>3,
    // source slot pre-swizzled so LDS (linear dest) holds XOR-swizzled layout
    int soffK[4], soffV[4];
    #pragma unroll
    for (int i = 0; i < 4; ++i) {
        const int ch = w * 256 + i * 64 + lane;
        const int r = ch >> 3;
        const int sc_ = ((ch & 7) ^ (r & 7)) * 8;
        soffK[i] = r * HDIM + sc_;          // + kt*64*HDIM per iter
        soffV[i] = r * SEQ + sc_;           // + kt*64 per iter
    }

    // Q fragments (B-operand): lane holds Q[q=nf*16+c][d=ch*32+g*8 ..+7]
    v8s qreg[2][2];
    const int q0 = qt * 64 + w * 32;
    #pragma unroll
    for (int nf = 0; nf < 2; ++nf)
        #pragma unroll
        for (int ch = 0; ch < 2; ++ch)
            qreg[nf][ch] = *reinterpret_cast<const v8s*>(
                qb + (size_t)(q0 + nf * 16 + c) * HDIM + ch * 32 + g * 8);

    v4f oacc[4][2];
    #pragma unroll
    for (int mf = 0; mf < 4; ++mf)
        #pragma unroll
        for (int nf = 0; nf < 2; ++nf) oacc[mf][nf] = (v4f)0.f;
    float m_[2] = {-3.0e38f, -3.0e38f}, l_[2] = {0.f, 0.f};

    // prologue: stage kt=0 into buf 0
    #pragma unroll
    for (int i = 0; i < 4; ++i) {
        const int ch = w * 256 + i * 64 + lane;
        __builtin_amdgcn_global_load_lds((gas_t)(kb + soffK[i]), (las_t)(&KT[0][ch * 8]), 16, 0, 0);
        __builtin_amdgcn_global_load_lds((gas_t)(vb + soffV[i]), (las_t)(&VT[0][ch * 8]), 16, 0, 0);
    }
    __syncthreads();

    for (int kt = 0; kt <= qt; ++kt) {
        const int cur = kt & 1;
        if (kt < qt) {       // async-stage next tile into other buffer
            const int kn = kt + 1;
            #pragma unroll
            for (int i = 0; i < 4; ++i) {
                const int ch = w * 256 + i * 64 + lane;
                __builtin_amdgcn_global_load_lds((gas_t)(kb + (size_t)kn * 64 * HDIM + soffK[i]),
                                                 (las_t)(&KT[cur ^ 1][ch * 8]), 16, 0, 0);
                __builtin_amdgcn_global_load_lds((gas_t)(vb + (size_t)kn * 64 + soffV[i]),
                                                 (las_t)(&VT[cur ^ 1][ch * 8]), 16, 0, 0);
            }
        }

        // ---- S^T = K * Q^T ----
        v4f sacc[4][2];
        #pragma unroll
        for (int mf = 0; mf < 4; ++mf)
            #pragma unroll
            for (int nf = 0; nf < 2; ++nf) sacc[mf][nf] = (v4f)0.f;
        #pragma unroll
        for (int ch = 0; ch < 2; ++ch) {
            v8s kf[4];
            #pragma unroll
            for (int mf = 0; mf < 4; ++mf) {
                const int row = mf * 16 + c;
                int idx = row * 64 + ch * 32 + g * 8;
                idx ^= (row & 7) << 3;
                kf[mf] = *reinterpret_cast<const v8s*>(&KT[cur][idx]);
            }
            #pragma unroll
            for (int mf = 0; mf < 4; ++mf)
                #pragma unroll
                for (int nf = 0; nf < 2; ++nf)
                    sacc[mf][nf] = __builtin_amdgcn_mfma_f32_16x16x32_bf16(
                        kf[mf], qreg[nf][ch], sacc[mf][nf], 0, 0, 0);
        }

        // causal mask on diagonal tile
        if (kt == qt) {
            #pragma unroll
            for (int mf = 0; mf < 4; ++mf)
                #pragma unroll
                for (int nf = 0; nf < 2; ++nf)
                    #pragma unroll
                    for (int j = 0; j < 4; ++j) {
                        const int kvl = mf * 16 + g * 4 + j;
                        const int ql  = w * 32 + nf * 16 + c;
                        if (kvl > ql) sacc[mf][nf][j] = -3.0e38f;
                    }
        }

        // ---- online softmax (per-lane per nf) + P -> swizzled LDS ----
        #pragma unroll
        for (int nf = 0; nf < 2; ++nf) {
            float pmax = -3.0e38f;
            #pragma unroll
            for (int mf = 0; mf < 4; ++mf)
                #pragma unroll
                for (int j = 0; j < 4; ++j) pmax = fmaxf(pmax, sacc[mf][nf][j]);
            pmax = fmaxf(pmax, __shfl_xor(pmax, 16));
            pmax = fmaxf(pmax, __shfl_xor(pmax, 32));
            const float mnew = fmaxf(m_[nf], pmax);
            const float sc = __expf(m_[nf] - mnew);
            m_[nf] = mnew;
            float rs = 0.f;
            #pragma unroll
            for (int mf = 0; mf < 4; ++mf) {
                float p0 = __expf(sacc[mf][nf][0] - mnew);
                float p1 = __expf(sacc[mf][nf][1] - mnew);
                float p2 = __expf(sacc[mf][nf][2] - mnew);
                float p3 = __expf(sacc[mf][nf][3] - mnew);
                rs += (p0 + p1) + (p2 + p3);
                const u32 w0 = (u32)f2bf(p0) | ((u32)f2bf(p1) << 16);
                const u32 w1 = (u32)f2bf(p2) | ((u32)f2bf(p3) << 16);
                const int qrow = nf * 16 + c;                // 0..31
                int idx0 = qrow * 64 + mf * 16 + g * 4;      // kv even
                idx0 ^= (qrow & 7) << 3;
                *reinterpret_cast<u32*>(&PL[w][idx0]) = w0;
                int idx1 = qrow * 64 + mf * 16 + g * 4 + 2;
                idx1 ^= (qrow & 7) << 3;
                *reinterpret_cast<u32*>(&PL[w][idx1]) = w1;
            }
            rs += __shfl_xor(rs, 16);
            rs += __shfl_xor(rs, 32);
            l_[nf] = l_[nf] * sc + rs;
            #pragma unroll
            for (int mf = 0; mf < 4; ++mf)
                #pragma unroll
                for (int j = 0; j < 4; ++j) oacc[mf][nf][j] *= sc;
        }

        // ---- O^T += V^T * P^T ----
        #pragma unroll
        for (int ch = 0; ch < 2; ++ch) {
            v8s vf[4], pf[2];
            #pragma unroll
            for (int mf = 0; mf < 4; ++mf) {
                const int row = mf * 16 + c;                 // d row
                int idx = row * 64 + ch * 32 + g * 8;
                idx ^= (row & 7) << 3;
                vf[mf] = *reinterpret_cast<const v8s*>(&VT[cur][idx]);
            }
            #pragma unroll
            for (int nf = 0; nf < 2; ++nf) {
                const int qrow = nf * 16 + c;
                int idx = qrow * 64 + ch * 32 + g * 8;
                idx ^= (qrow & 7) << 3;
                pf[nf] = *reinterpret_cast<const v8s*>(&PL[w][idx]);
            }
            #pragma unroll
            for (int mf = 0; mf < 4; ++mf)
                #pragma unroll
                for (int nf = 0; nf < 2; ++nf)
                    oacc[mf][nf] = __builtin_amdgcn_mfma_f32_16x16x32_bf16(
                        vf[mf], pf[nf], oacc[mf][nf], 0, 0, 0);
        }
        __syncthreads();   // drains vmcnt (next tile staged) + protects buffers
    }

    // epilogue: O^T element (d = mf*16+g*4+j, q = nf*16+c); write hi/lo bf16
    #pragma unroll
    for (int nf = 0; nf < 2; ++nf) {
        const float inv = 1.0f / l_[nf];
        const size_t row = (size_t)bb * SEQ + q0 + nf * 16 + c;   // token
        #pragma unroll
        for (int mf = 0; mf < 4; ++mf) {
            float v0 = oacc[mf][nf][0] * inv, v1 = oacc[mf][nf][1] * inv;
            float v2 = oacc[mf][nf][2] * inv, v3 = oacc[mf][nf][3] * inv;
            U16x4 hv, lv;
            splitbf(v0, hv.x, lv.x); splitbf(v1, hv.y, lv.y);
            splitbf(v2, hv.z, lv.z); splitbf(v3, hv.w, lv.w);
            const size_t off = row * EMB + hh * HDIM + mf * 16 + g * 4;
            *reinterpret_cast<U16x4*>(ohi + off) = hv;
            *reinterpret_cast<U16x4*>(olo + off) = lv;
        }
    }
}

// ---------------------------------------------------------------- launch
extern "C" void kernel_launch(void* const* d_in, const int* in_sizes, int n_in,
                              void* d_out, int out_size, void* d_ws, size_t ws_size,
                              hipStream_t stream)
{
    const int*   tokens  = (const int*)  d_in[0];
    const float* tok_emb = (const float*)d_in[1];
    const float* pos_emb = (const float*)d_in[2];
    const float* Wq      = (const float*)d_in[3];
    const float* Wk      = (const float*)d_in[4];
    const float* Wv      = (const float*)d_in[5];
    const float* Wo      = (const float*)d_in[6];
    const float* bo      = (const float*)d_in[7];
    const float* ln1_g   = (const float*)d_in[8];
    const float* ln1_b   = (const float*)d_in[9];
    const float* ln2_g   = (const float*)d_in[10];
    const float* ln2_b   = (const float*)d_in[11];
    const float* W1      = (const float*)d_in[12];
    const float* b1      = (const float*)d_in[13];
    const float* W2      = (const float*)d_in[14];
    const float* b2      = (const float*)d_in[15];
    const float* lnf_g   = (const float*)d_in[16];
    const float* lnf_b   = (const float*)d_in[17];
    const float* Wlm     = (const float*)d_in[18];
    const float* blm     = (const float*)d_in[19];
    float* out = (float*)d_out;

    // workspace: x fp32 (8MB) | 32MB region {q,k,v,ohi,olo bf16 (20MB)} aliased
    // by {ff hi/lo bf16 (32MB)} | h hi/lo (8MB) | transposed split weights (~67MB)
    const size_t NE = (size_t)NTOK * EMB;            // 2097152
    const size_t NF = (size_t)NTOK * FFD;            // 8388608
    float* x   = (float*)d_ws;
    float* zr  = x + NE;
    u16* qb16  = (u16*)zr;
    u16* kb16  = qb16 + NE;
    u16* vb16  = kb16 + NE;                          // [B,H,D,T]
    u16* ohi   = vb16 + NE;
    u16* olo   = ohi + NE;
    u16* ffhi  = (u16*)zr;                           // aliases q..olo (disjoint lifetime)
    u16* fflo  = ffhi + NF;
    u16* hhi   = (u16*)(zr + 4 * NE);
    u16* hlo   = hhi + NE;

    const size_t SQKV = (size_t)4 * 1536 * 512;
    const size_t SWO  = (size_t)4 * 512 * 512;
    const size_t SW1  = (size_t)4 * 2048 * 512;
    const size_t SLM  = (size_t)8064 * 512;
    u16* qkvT_h = hlo + NE;        u16* qkvT_l = qkvT_h + SQKV;
    u16* woT_h  = qkvT_l + SQKV;   u16* woT_l  = woT_h + SWO;
    u16* w1T_h  = woT_l + SWO;     u16* w1T_l  = w1T_h + SW1;
    u16* w2T_h  = w1T_l + SW1;     u16* w2T_l  = w2T_h + SW1;
    u16* wlmT_h = w2T_l + SW1;     u16* wlmT_l = wlmT_h + SLM;

    // ---- weight prep: one dispatch for all five transpose/split jobs ----
    prep_weights<<<16320, 256, 0, stream>>>(Wq, Wk, Wv, Wo, W1, W2, Wlm,
                                            qkvT_h, qkvT_l, woT_h, woT_l,
                                            w1T_h, w1T_l, w2T_h, w2T_l,
                                            wlmT_h, wlmT_l);

    embed_kernel<<<NTOK, 128, 0, stream>>>(tokens, tok_emb, pos_emb, x);

    for (int l = 0; l < 4; ++l) {
        ln_split_kernel<<<NTOK / 4, 256, 0, stream>>>(x, ln1_g + l * EMB, ln1_b + l * EMB,
                                                      hhi, hlo);
        gemm_mfma<2, EPI_QKV><<<dim3(12, 32), 256, 0, stream>>>(
            hhi, hlo, qkvT_h + (size_t)l * 1536 * 512, qkvT_l + (size_t)l * 1536 * 512,
            nullptr, EMB, 1536, nullptr, qb16, kb16, vb16);

        attn_mfma<<<dim3(32, 16), 128, 0, stream>>>(qb16, kb16, vb16, ohi, olo);

        gemm_mfma<0, EPI_RES><<<dim3(8, 64), 256, 0, stream>>>(
            ohi, olo, woT_h + (size_t)l * 262144, woT_l + (size_t)l * 262144,
            bo + l * EMB, EMB, EMB, x, nullptr, nullptr, nullptr);

        ln_split_kernel<<<NTOK / 4, 256, 0, stream>>>(x, ln2_g + l * EMB, ln2_b + l * EMB,
                                                      hhi, hlo);
        gemm_mfma<2, EPI_RELU_SPLIT><<<dim3(16, 32), 256, 0, stream>>>(
            hhi, hlo, w1T_h + (size_t)l * 1048576, w1T_l + (size_t)l * 1048576,
            b1 + l * FFD, EMB, FFD, nullptr, ffhi, fflo, nullptr);

        gemm_mfma<0, EPI_RES><<<dim3(8, 64), 256, 0, stream>>>(
            ffhi, fflo, w2T_h + (size_t)l * 1048576, w2T_l + (size_t)l * 1048576,
            b2 + l * EMB, FFD, EMB, x, nullptr, nullptr, nullptr);
    }

    ln_split_kernel<<<NTOK / 4, 256, 0, stream>>>(x, lnf_g, lnf_b, hhi, hlo);

    gemm_mfma<2, EPI_OUT><<<dim3(63, 32), 256, 0, stream>>>(
        hhi, hlo, wlmT_h, wlmT_l, blm, EMB, VOCAB, out, nullptr, nullptr, nullptr);
}

// Round 9
// 1031.918 us; speedup vs baseline: 2.0210x; 1.0512x over previous
//
#include <hip/hip_runtime.h>
#include <hip/hip_bf16.h>

#define NH 8
#define EMB 512
#define HDIM 64
#define SEQ 2048
#define VOCAB 8000
#define NTOK 4096
#define FFD 2048
#define LN_EPS 1e-5f
#define SM_SCALE 0.04419417382415922f   // 512^-0.5 (reference scales by E, not DH)

typedef unsigned short u16;
typedef unsigned int u32;
typedef short v8s __attribute__((ext_vector_type(8)));   // 8 bf16 in 4 VGPRs
typedef float v4f __attribute__((ext_vector_type(4)));   // MFMA accumulator

typedef const __attribute__((address_space(1))) void* gas_t;
typedef __attribute__((address_space(3))) void* las_t;

struct __align__(8) U16x4 { u16 x, y, z, w; };

__device__ __forceinline__ u16 f2bf(float x) {
    union { float f; unsigned int u; } c; c.f = x;
    return (u16)((c.u + 0x7FFFu + ((c.u >> 16) & 1u)) >> 16);   // RNE
}
__device__ __forceinline__ float bf2f(u16 b) {
    union { unsigned int u; float f; } c; c.u = ((unsigned int)b) << 16; return c.f;
}
__device__ __forceinline__ void splitbf(float x, u16& hi, u16& lo) {
    hi = f2bf(x);
    lo = f2bf(x - bf2f(hi));
}

// ---------------------------------------------------------------- embed
__global__ __launch_bounds__(128)
void embed_kernel(const int* __restrict__ tokens, const float* __restrict__ tok_emb,
                  const float* __restrict__ pos_emb, float* __restrict__ x)
{
    const int row = blockIdx.x;            // b*SEQ + t
    const int t   = row & (SEQ - 1);
    const int tok = tokens[row];
    const int c   = threadIdx.x * 4;
    const float4 a = *reinterpret_cast<const float4*>(tok_emb + (size_t)tok * EMB + c);
    const float4 p = *reinterpret_cast<const float4*>(pos_emb + (size_t)t * EMB + c);
    float4 r; r.x = a.x + p.x; r.y = a.y + p.y; r.z = a.z + p.z; r.w = a.w + p.w;
    *reinterpret_cast<float4*>(x + (size_t)row * EMB + c) = r;
}

// ---------------------------------------------------------------- merged weight prep
// All five transpose+split jobs in ONE dispatch (one 32x32 tile per block).
// src fp32 [R-dim rows][C-dim cols]; dst bf16 hi/lo [C(padded)][R].
__global__ __launch_bounds__(256)
void prep_weights(const float* __restrict__ Wq, const float* __restrict__ Wk,
                  const float* __restrict__ Wv, const float* __restrict__ Wo,
                  const float* __restrict__ W1, const float* __restrict__ W2,
                  const float* __restrict__ Wlm,
                  u16* __restrict__ qkvT_h, u16* __restrict__ qkvT_l,
                  u16* __restrict__ woT_h,  u16* __restrict__ woT_l,
                  u16* __restrict__ w1T_h,  u16* __restrict__ w1T_l,
                  u16* __restrict__ w2T_h,  u16* __restrict__ w2T_l,
                  u16* __restrict__ wlmT_h, u16* __restrict__ wlmT_l)
{
    const int t = blockIdx.x;
    const float* src; u16 *dh, *dl; int R, C, ct, rt;
    if (t < 3072) {                                  // QKV: 96 z * (2 x * 16 y)
        const int z = t >> 5, rem = t & 31;
        const int l = z / 24, r2 = z % 24, sel = r2 >> 3, h = r2 & 7;
        src = (sel == 0 ? Wq : sel == 1 ? Wk : Wv) + (size_t)(l * 8 + h) * EMB * HDIM;
        const size_t dbase = ((size_t)l * 1536 + sel * 512 + h * 64) * EMB;
        dh = qkvT_h + dbase; dl = qkvT_l + dbase;
        R = EMB; C = HDIM; ct = (rem & 1) * 32; rt = (rem >> 1) * 32;
    } else if (t < 4096) {                           // Wo: 4 z * (16 x * 16 y)
        const int t2 = t - 3072, z = t2 >> 8, rem = t2 & 255;
        src = Wo + (size_t)z * 262144;
        dh = woT_h + (size_t)z * 262144; dl = woT_l + (size_t)z * 262144;
        R = 512; C = 512; ct = (rem & 15) * 32; rt = (rem >> 4) * 32;
    } else if (t < 8192) {                           // W1: 4 z * (64 x * 16 y)
        const int t3 = t - 4096, z = t3 >> 10, rem = t3 & 1023;
        src = W1 + (size_t)z * 1048576;
        dh = w1T_h + (size_t)z * 1048576; dl = w1T_l + (size_t)z * 1048576;
        R = 512; C = 2048; ct = (rem & 63) * 32; rt = (rem >> 6) * 32;
    } else if (t < 12288) {                          // W2: 4 z * (16 x * 64 y)
        const int t4 = t - 8192, z = t4 >> 10, rem = t4 & 1023;
        src = W2 + (size_t)z * 1048576;
        dh = w2T_h + (size_t)z * 1048576; dl = w2T_l + (size_t)z * 1048576;
        R = 2048; C = 512; ct = (rem & 15) * 32; rt = (rem >> 4) * 32;
    } else {                                         // Wlm: 252 x * 16 y
        const int t5 = t - 12288;
        src = Wlm; dh = wlmT_h; dl = wlmT_l;
        R = 512; C = 8000; ct = (t5 % 252) * 32; rt = (t5 / 252) * 32;
    }

    __shared__ float sh[32][33];
    const int cx = threadIdx.x & 31, ry = threadIdx.x >> 5;
    #pragma unroll
    for (int i = 0; i < 4; ++i) {
        const int r = ry + i * 8;
        float v = 0.f;
        if (ct + cx < C) v = src[(size_t)(rt + r) * C + ct + cx];
        sh[r][cx] = v;
    }
    __syncthreads();
    #pragma unroll
    for (int i = 0; i < 4; ++i) {
        const int r = ry + i * 8;
        u16 hi, lo; splitbf(sh[cx][r], hi, lo);
        const size_t o = (size_t)(ct + r) * R + rt + cx;
        dh[o] = hi; dl[o] = lo;
    }
}

// ---------------------------------------------------------------- layernorm -> bf16 hi/lo
__global__ __launch_bounds__(256)
void ln_split_kernel(const float* __restrict__ x, const float* __restrict__ g,
                     const float* __restrict__ b, u16* __restrict__ hhi,
                     u16* __restrict__ hlo)
{
    const int row  = blockIdx.x * 4 + (threadIdx.x >> 6);
    const int lane = threadIdx.x & 63;
    const float* xp = x + (size_t)row * EMB;
    const float4 v0 = *reinterpret_cast<const float4*>(xp + lane * 4);
    const float4 v1 = *reinterpret_cast<const float4*>(xp + lane * 4 + 256);

    float s = v0.x + v0.y + v0.z + v0.w + v1.x + v1.y + v1.z + v1.w;
    #pragma unroll
    for (int off = 32; off > 0; off >>= 1) s += __shfl_xor(s, off);
    const float mean = s * (1.0f / EMB);

    float dx[8] = {v0.x - mean, v0.y - mean, v0.z - mean, v0.w - mean,
                   v1.x - mean, v1.y - mean, v1.z - mean, v1.w - mean};
    float vs = 0.f;
    #pragma unroll
    for (int u = 0; u < 8; ++u) vs = fmaf(dx[u], dx[u], vs);
    #pragma unroll
    for (int off = 32; off > 0; off >>= 1) vs += __shfl_xor(vs, off);
    const float inv = 1.0f / sqrtf(vs * (1.0f / EMB) + LN_EPS);

    const float4 g0 = *reinterpret_cast<const float4*>(g + lane * 4);
    const float4 g1 = *reinterpret_cast<const float4*>(g + lane * 4 + 256);
    const float4 b0 = *reinterpret_cast<const float4*>(b + lane * 4);
    const float4 b1 = *reinterpret_cast<const float4*>(b + lane * 4 + 256);
    float ov[8];
    ov[0] = fmaf(dx[0] * inv, g0.x, b0.x); ov[1] = fmaf(dx[1] * inv, g0.y, b0.y);
    ov[2] = fmaf(dx[2] * inv, g0.z, b0.z); ov[3] = fmaf(dx[3] * inv, g0.w, b0.w);
    ov[4] = fmaf(dx[4] * inv, g1.x, b1.x); ov[5] = fmaf(dx[5] * inv, g1.y, b1.y);
    ov[6] = fmaf(dx[6] * inv, g1.z, b1.z); ov[7] = fmaf(dx[7] * inv, g1.w, b1.w);

    U16x4 h0, l0, h1, l1;
    splitbf(ov[0], h0.x, l0.x); splitbf(ov[1], h0.y, l0.y);
    splitbf(ov[2], h0.z, l0.z); splitbf(ov[3], h0.w, l0.w);
    splitbf(ov[4], h1.x, l1.x); splitbf(ov[5], h1.y, l1.y);
    splitbf(ov[6], h1.z, l1.z); splitbf(ov[7], h1.w, l1.w);
    const size_t o = (size_t)row * EMB + lane * 4;
    *reinterpret_cast<U16x4*>(hhi + o)       = h0;
    *reinterpret_cast<U16x4*>(hhi + o + 256) = h1;
    *reinterpret_cast<U16x4*>(hlo + o)       = l0;
    *reinterpret_cast<U16x4*>(hlo + o + 256) = l1;
}

// ---------------------------------------------------------------- split-bf16 MFMA GEMM
// A (hi/lo bf16) [M=4096][K] row-major; Bt (hi/lo bf16) [N][K] row-major.
// WMC=2: 128x128 (2x2 waves, 4x4 frags). WMC=1: 64x128 (1x4 waves, 4x2 frags).
// WMC=0: 64x64 (2x2 waves, 2x2 frags).
// Double-buffered LDS (1 barrier/K-step), XOR-swizzled LDS (pre-swizzled global
// source, rule #21), XCD-aware bijective block swizzle.
enum { EPI_QKV = 0, EPI_RES = 1, EPI_RELU_SPLIT = 2, EPI_OUT = 3 };

template<int WMC, int EPI>
__global__ __launch_bounds__(256)
void gemm_mfma(const u16* __restrict__ Ah, const u16* __restrict__ Al,
               const u16* __restrict__ Bh, const u16* __restrict__ Bl,
               const float* __restrict__ bias, int K, int N,
               float* o0,
               u16* __restrict__ u0, u16* __restrict__ u1, u16* __restrict__ u2)
{
    constexpr int BM = (WMC == 2) ? 128 : 64;
    constexpr int BN = (WMC == 0) ? 64 : 128;
    constexpr int MFRAG = (WMC == 0) ? 2 : 4;
    constexpr int NFRAG = (WMC == 2) ? 4 : 2;

    __shared__ __align__(16) u16 AhS[2][BM * 32], AlS[2][BM * 32];
    __shared__ __align__(16) u16 BhS[2][BN * 32], BlS[2][BN * 32];

    const int tid  = threadIdx.x;
    const int lane = tid & 63, w = tid >> 6;
    int moff, noff;
    if constexpr (WMC == 2)      { moff = (w >> 1) * 64; noff = (w & 1) * 64; }
    else if constexpr (WMC == 1) { moff = 0;             noff = w * 32;       }
    else                         { moff = (w >> 1) * 32; noff = (w & 1) * 32; }

    // XCD-aware bijective swizzle (all grids have nwg % 8 == 0), column-major
    // chunked so each XCD owns a contiguous run of B-panels (L2-resident).
    const int gy = (int)gridDim.y;
    int bid = (int)blockIdx.x * gy + (int)blockIdx.y;
    const int cpx = ((int)gridDim.x * gy) >> 3;
    bid = (bid & 7) * cpx + (bid >> 3);
    const int m0 = (bid % gy) * BM, n0 = (bid / gy) * BN;

    v4f acc[MFRAG][NFRAG];
    #pragma unroll
    for (int mi = 0; mi < MFRAG; ++mi)
        #pragma unroll
        for (int ni = 0; ni < NFRAG; ++ni) acc[mi][ni] = (v4f)0.f;

    const int arow = lane & 15, kgi = lane >> 4;

    // stage K-slab k0 into LDS buffer buf. LDS dest is linear (chunk order);
    // global source column-group is XOR-swizzled: L[r][cg] = G[r][cg^((r>>1)&3)]
    auto stage = [&](int buf, int k0) {
        #pragma unroll
        for (int u = 0; u < BM / 64; ++u) {
            const int ch = u * 256 + tid;
            const int r = ch >> 2, cg = ch & 3;
            const int sc8 = (cg ^ ((r >> 1) & 3)) * 8;
            const size_t go = (size_t)(m0 + r) * K + k0 + sc8;
            __builtin_amdgcn_global_load_lds((gas_t)(Ah + go), (las_t)(&AhS[buf][ch * 8]), 16, 0, 0);
            __builtin_amdgcn_global_load_lds((gas_t)(Al + go), (las_t)(&AlS[buf][ch * 8]), 16, 0, 0);
        }
        #pragma unroll
        for (int u = 0; u < BN / 64; ++u) {
            const int ch = u * 256 + tid;
            const int r = ch >> 2, cg = ch & 3;
            const int sc8 = (cg ^ ((r >> 1) & 3)) * 8;
            const size_t go = (size_t)(n0 + r) * K + k0 + sc8;
            __builtin_amdgcn_global_load_lds((gas_t)(Bh + go), (las_t)(&BhS[buf][ch * 8]), 16, 0, 0);
            __builtin_amdgcn_global_load_lds((gas_t)(Bl + go), (las_t)(&BlS[buf][ch * 8]), 16, 0, 0);
        }
    };

    stage(0, 0);
    const int NK = K >> 5;
    for (int ks = 0; ks < NK; ++ks) {
        const int cur = ks & 1;
        __syncthreads();                       // staged(cur) done; prior reads of cur^1 done
        if (ks + 1 < NK) stage(cur ^ 1, (ks + 1) * 32);

        v8s ah[MFRAG], al[MFRAG], bh[NFRAG], bl[NFRAG];
        #pragma unroll
        for (int mi = 0; mi < MFRAG; ++mi) {
            const int ar = moff + mi * 16 + arow;
            const int idx = ar * 32 + (kgi ^ ((ar >> 1) & 3)) * 8;
            ah[mi] = *reinterpret_cast<const v8s*>(&AhS[cur][idx]);
            al[mi] = *reinterpret_cast<const v8s*>(&AlS[cur][idx]);
        }
        #pragma unroll
        for (int ni = 0; ni < NFRAG; ++ni) {
            const int br = noff + ni * 16 + arow;
            const int idx = br * 32 + (kgi ^ ((br >> 1) & 3)) * 8;
            bh[ni] = *reinterpret_cast<const v8s*>(&BhS[cur][idx]);
            bl[ni] = *reinterpret_cast<const v8s*>(&BlS[cur][idx]);
        }
        #pragma unroll
        for (int mi = 0; mi < MFRAG; ++mi)
            #pragma unroll
            for (int ni = 0; ni < NFRAG; ++ni) {
                acc[mi][ni] = __builtin_amdgcn_mfma_f32_16x16x32_bf16(ah[mi], bh[ni], acc[mi][ni], 0, 0, 0);
                acc[mi][ni] = __builtin_amdgcn_mfma_f32_16x16x32_bf16(ah[mi], bl[ni], acc[mi][ni], 0, 0, 0);
                acc[mi][ni] = __builtin_amdgcn_mfma_f32_16x16x32_bf16(al[mi], bh[ni], acc[mi][ni], 0, 0, 0);
            }
    }

    // epilogue: C/D layout row=(lane>>4)*4+j, col=lane&15
    const int crow0 = (lane >> 4) * 4;
    const int ccol  = lane & 15;
    #pragma unroll
    for (int mi = 0; mi < MFRAG; ++mi) {
        const int mbase = m0 + moff + mi * 16 + crow0;
        #pragma unroll
        for (int ni = 0; ni < NFRAG; ++ni) {
            const int n = n0 + noff + ni * 16 + ccol;
            if constexpr (EPI == EPI_QKV) {
                // q: bf16*SM_SCALE [B,H,T,D]; k: bf16 [B,H,T,D]; v: bf16 [B,H,D,T]
                const int sel = n >> 9, hh = (n >> 6) & 7, dd = n & 63;
                const int bbb = mbase >> 11, t = mbase & (SEQ - 1);
                if (sel == 2) {
                    U16x4 pv;
                    pv.x = f2bf(acc[mi][ni][0]); pv.y = f2bf(acc[mi][ni][1]);
                    pv.z = f2bf(acc[mi][ni][2]); pv.w = f2bf(acc[mi][ni][3]);
                    *reinterpret_cast<U16x4*>(
                        u2 + ((size_t)((bbb * NH + hh) * HDIM + dd) * SEQ + t)) = pv;
                } else {
                    u16* dst = sel ? u1 : u0;
                    const float scl = sel ? 1.0f : SM_SCALE;
                    #pragma unroll
                    for (int j = 0; j < 4; ++j) {
                        const int m = mbase + j;
                        dst[((size_t)((m >> 11) * NH + hh) * SEQ + (m & (SEQ - 1))) * HDIM + dd]
                            = f2bf(acc[mi][ni][j] * scl);
                    }
                }
            } else if constexpr (EPI == EPI_RES) {
                const float bv = bias[n];
                #pragma unroll
                for (int j = 0; j < 4; ++j) {
                    const size_t o = (size_t)(mbase + j) * N + n;
                    o0[o] = o0[o] + acc[mi][ni][j] + bv;
                }
            } else if constexpr (EPI == EPI_RELU_SPLIT) {
                const float bv = bias[n];
                #pragma unroll
                for (int j = 0; j < 4; ++j) {
                    const float v_ = fmaxf(acc[mi][ni][j] + bv, 0.f);
                    u16 hi, lo; splitbf(v_, hi, lo);
                    const size_t o = (size_t)(mbase + j) * N + n;
                    u0[o] = hi; u1[o] = lo;
                }
            } else {                                    // EPI_OUT (LM head, ragged N)
                if (n < N) {
                    const float bv = bias[n];
                    #pragma unroll
                    for (int j = 0; j < 4; ++j)
                        o0[(size_t)(mbase + j) * N + n] = acc[mi][ni][j] + bv;
                }
            }
        }
    }
}

// ---------------------------------------------------------------- MFMA flash attention
// 32 q-rows per block (2 waves x 16 q), KV tile 64; grid (64 qt, 16 bh) = 1024
// blocks -> 4 blocks/CU (LDS 36KB), 2 waves/SIMD. Shared K/V staging, per-wave P.
// S^T = K*Q^T (per-lane softmax state); O^T = V^T*P^T. qt direction alternates
// with bh-half so co-resident blocks balance.
__global__ __launch_bounds__(128)
void attn_mfma(const u16* __restrict__ qg, const u16* __restrict__ kg,
               const u16* __restrict__ vg, u16* __restrict__ ohi,
               u16* __restrict__ olo)
{
    __shared__ __align__(16) u16 KT[2][4096];   // swizzled [kv 64][d 64]
    __shared__ __align__(16) u16 VT[2][4096];   // swizzled [d 64][kv 64]
    __shared__ __align__(16) u16 PL[2][1024];   // per-wave, swizzled [q 16][kv 64]

    const int tid = threadIdx.x, lane = tid & 63, w = tid >> 6;
    const int g = lane >> 4, c = lane & 15;
    const int bh = blockIdx.y;
    const int qt = (bh & 8) ? (int)blockIdx.x : 63 - (int)blockIdx.x;  // 0..63
    const int bb = bh >> 3, hh = bh & 7;
    const int nkv = (qt >> 1) + 1;              // 64-wide kv tiles needed

    const u16* qb = qg + (size_t)bh * (SEQ * HDIM);
    const u16* kb = kg + (size_t)bh * (SEQ * HDIM);
    const u16* vb = vg + (size_t)bh * (HDIM * SEQ);

    // staging (both waves cooperate): chunk = w*256 + i*64 + lane; row=chunk>>3,
    // source slot pre-swizzled so LDS (linear dest) holds XOR-swizzled layout
    int soffK[4], soffV[4];
    #pragma unroll
    for (int i = 0; i < 4; ++i) {
        const int ch = w * 256 + i * 64 + lane;
        const int r = ch >> 3;
        const int sc_ = ((ch & 7) ^ (r & 7)) * 8;
        soffK[i] = r * HDIM + sc_;          // + kt*64*HDIM per iter
        soffV[i] = r * SEQ + sc_;           // + kt*64 per iter
    }

    // Q fragment (B-operand): wave w covers q rows [qt*32 + w*16, +16)
    v8s qreg[2];
    const int qrow = qt * 32 + w * 16 + c;
    #pragma unroll
    for (int ch = 0; ch < 2; ++ch)
        qreg[ch] = *reinterpret_cast<const v8s*>(
            qb + (size_t)qrow * HDIM + ch * 32 + g * 8);

    v4f oacc[4];
    #pragma unroll
    for (int mf = 0; mf < 4; ++mf) oacc[mf] = (v4f)0.f;
    float m_ = -3.0e38f, l_ = 0.f;

    // prologue: stage kt=0 into buf 0
    #pragma unroll
    for (int i = 0; i < 4; ++i) {
        const int ch = w * 256 + i * 64 + lane;
        __builtin_amdgcn_global_load_lds((gas_t)(kb + soffK[i]), (las_t)(&KT[0][ch * 8]), 16, 0, 0);
        __builtin_amdgcn_global_load_lds((gas_t)(vb + soffV[i]), (las_t)(&VT[0][ch * 8]), 16, 0, 0);
    }
    __syncthreads();

    for (int kt = 0; kt < nkv; ++kt) {
        const int cur = kt & 1;
        if (kt + 1 < nkv) {  // async-stage next tile into other buffer
            const int kn = kt + 1;
            #pragma unroll
            for (int i = 0; i < 4; ++i) {
                const int ch = w * 256 + i * 64 + lane;
                __builtin_amdgcn_global_load_lds((gas_t)(kb + (size_t)kn * 64 * HDIM + soffK[i]),
                                                 (las_t)(&KT[cur ^ 1][ch * 8]), 16, 0, 0);
                __builtin_amdgcn_global_load_lds((gas_t)(vb + (size_t)kn * 64 + soffV[i]),
                                                 (las_t)(&VT[cur ^ 1][ch * 8]), 16, 0, 0);
            }
        }

        // ---- S^T = K * Q^T ----
        v4f sacc[4];
        #pragma unroll
        for (int mf = 0; mf < 4; ++mf) sacc[mf] = (v4f)0.f;
        __builtin_amdgcn_s_setprio(1);
        #pragma unroll
        for (int ch = 0; ch < 2; ++ch) {
            v8s kf[4];
            #pragma unroll
            for (int mf = 0; mf < 4; ++mf) {
                const int row = mf * 16 + c;
                int idx = row * 64 + ch * 32 + g * 8;
                idx ^= (row & 7) << 3;
                kf[mf] = *reinterpret_cast<const v8s*>(&KT[cur][idx]);
            }
            #pragma unroll
            for (int mf = 0; mf < 4; ++mf)
                sacc[mf] = __builtin_amdgcn_mfma_f32_16x16x32_bf16(
                    kf[mf], qreg[ch], sacc[mf], 0, 0, 0);
        }
        __builtin_amdgcn_s_setprio(0);

        // causal mask on last kv tile: kv_local > q_local within the 64-tile
        if (kt == nkv - 1) {
            const int qloc = ((qt & 1) << 5) + w * 16 + c;
            #pragma unroll
            for (int mf = 0; mf < 4; ++mf)
                #pragma unroll
                for (int j = 0; j < 4; ++j) {
                    const int kvl = mf * 16 + g * 4 + j;
                    if (kvl > qloc) sacc[mf][j] = -3.0e38f;
                }
        }

        // ---- online softmax (per-lane) + P -> swizzled per-wave LDS ----
        {
            float pmax = -3.0e38f;
            #pragma unroll
            for (int mf = 0; mf < 4; ++mf)
                #pragma unroll
                for (int j = 0; j < 4; ++j) pmax = fmaxf(pmax, sacc[mf][j]);
            pmax = fmaxf(pmax, __shfl_xor(pmax, 16));
            pmax = fmaxf(pmax, __shfl_xor(pmax, 32));
            const float mnew = fmaxf(m_, pmax);
            const float sc = __expf(m_ - mnew);
            m_ = mnew;
            float rs = 0.f;
            #pragma unroll
            for (int mf = 0; mf < 4; ++mf) {
                float p0 = __expf(sacc[mf][0] - mnew);
                float p1 = __expf(sacc[mf][1] - mnew);
                float p2 = __expf(sacc[mf][2] - mnew);
                float p3 = __expf(sacc[mf][3] - mnew);
                rs += (p0 + p1) + (p2 + p3);
                const u32 w0 = (u32)f2bf(p0) | ((u32)f2bf(p1) << 16);
                const u32 w1 = (u32)f2bf(p2) | ((u32)f2bf(p3) << 16);
                int idx0 = c * 64 + mf * 16 + g * 4;      // q row = c (0..15)
                idx0 ^= (c & 7) << 3;
                *reinterpret_cast<u32*>(&PL[w][idx0]) = w0;
                int idx1 = c * 64 + mf * 16 + g * 4 + 2;
                idx1 ^= (c & 7) << 3;
                *reinterpret_cast<u32*>(&PL[w][idx1]) = w1;
            }
            rs += __shfl_xor(rs, 16);
            rs += __shfl_xor(rs, 32);
            l_ = l_ * sc + rs;
            #pragma unroll
            for (int mf = 0; mf < 4; ++mf)
                #pragma unroll
                for (int j = 0; j < 4; ++j) oacc[mf][j] *= sc;
        }

        // ---- O^T += V^T * P^T ----
        __builtin_amdgcn_s_setprio(1);
        #pragma unroll
        for (int ch = 0; ch < 2; ++ch) {
            v8s vf[4], pf;
            #pragma unroll
            for (int mf = 0; mf < 4; ++mf) {
                const int row = mf * 16 + c;                 // d row
                int idx = row * 64 + ch * 32 + g * 8;
                idx ^= (row & 7) << 3;
                vf[mf] = *reinterpret_cast<const v8s*>(&VT[cur][idx]);
            }
            {
                int idx = c * 64 + ch * 32 + g * 8;
                idx ^= (c & 7) << 3;
                pf = *reinterpret_cast<const v8s*>(&PL[w][idx]);
            }
            #pragma unroll
            for (int mf = 0; mf < 4; ++mf)
                oacc[mf] = __builtin_amdgcn_mfma_f32_16x16x32_bf16(
                    vf[mf], pf, oacc[mf], 0, 0, 0);
        }
        __builtin_amdgcn_s_setprio(0);
        __syncthreads();   // drains vmcnt (next tile staged) + protects buffers
    }

    // epilogue: O^T element (d = mf*16+g*4+j, q = qrow); write hi/lo bf16
    {
        const float inv = 1.0f / l_;
        const size_t row = (size_t)bb * SEQ + qrow;   // token
        #pragma unroll
        for (int mf = 0; mf < 4; ++mf) {
            float v0 = oacc[mf][0] * inv, v1 = oacc[mf][1] * inv;
            float v2 = oacc[mf][2] * inv, v3 = oacc[mf][3] * inv;
            U16x4 hv, lv;
            splitbf(v0, hv.x, lv.x); splitbf(v1, hv.y, lv.y);
            splitbf(v2, hv.z, lv.z); splitbf(v3, hv.w, lv.w);
            const size_t off = row * EMB + hh * HDIM + mf * 16 + g * 4;
            *reinterpret_cast<U16x4*>(ohi + off) = hv;
            *reinterpret_cast<U16x4*>(olo + off) = lv;
        }
    }
}

// ---------------------------------------------------------------- launch
extern "C" void kernel_launch(void* const* d_in, const int* in_sizes, int n_in,
                              void* d_out, int out_size, void* d_ws, size_t ws_size,
                              hipStream_t stream)
{
    const int*   tokens  = (const int*)  d_in[0];
    const float* tok_emb = (const float*)d_in[1];
    const float* pos_emb = (const float*)d_in[2];
    const float* Wq      = (const float*)d_in[3];
    const float* Wk      = (const float*)d_in[4];
    const float* Wv      = (const float*)d_in[5];
    const float* Wo      = (const float*)d_in[6];
    const float* bo      = (const float*)d_in[7];
    const float* ln1_g   = (const float*)d_in[8];
    const float* ln1_b   = (const float*)d_in[9];
    const float* ln2_g   = (const float*)d_in[10];
    const float* ln2_b   = (const float*)d_in[11];
    const float* W1      = (const float*)d_in[12];
    const float* b1      = (const float*)d_in[13];
    const float* W2      = (const float*)d_in[14];
    const float* b2      = (const float*)d_in[15];
    const float* lnf_g   = (const float*)d_in[16];
    const float* lnf_b   = (const float*)d_in[17];
    const float* Wlm     = (const float*)d_in[18];
    const float* blm     = (const float*)d_in[19];
    float* out = (float*)d_out;

    // workspace: x fp32 (8MB) | 32MB region {q,k,v,ohi,olo bf16 (20MB)} aliased
    // by {ff hi/lo bf16 (32MB)} | h hi/lo (8MB) | transposed split weights (~67MB)
    const size_t NE = (size_t)NTOK * EMB;            // 2097152
    const size_t NF = (size_t)NTOK * FFD;            // 8388608
    float* x   = (float*)d_ws;
    float* zr  = x + NE;
    u16* qb16  = (u16*)zr;
    u16* kb16  = qb16 + NE;
    u16* vb16  = kb16 + NE;                          // [B,H,D,T]
    u16* ohi   = vb16 + NE;
    u16* olo   = ohi + NE;
    u16* ffhi  = (u16*)zr;                           // aliases q..olo (disjoint lifetime)
    u16* fflo  = ffhi + NF;
    u16* hhi   = (u16*)(zr + 4 * NE);
    u16* hlo   = hhi + NE;

    const size_t SQKV = (size_t)4 * 1536 * 512;
    const size_t SWO  = (size_t)4 * 512 * 512;
    const size_t SW1  = (size_t)4 * 2048 * 512;
    const size_t SLM  = (size_t)8064 * 512;
    u16* qkvT_h = hlo + NE;        u16* qkvT_l = qkvT_h + SQKV;
    u16* woT_h  = qkvT_l + SQKV;   u16* woT_l  = woT_h + SWO;
    u16* w1T_h  = woT_l + SWO;     u16* w1T_l  = w1T_h + SW1;
    u16* w2T_h  = w1T_l + SW1;     u16* w2T_l  = w2T_h + SW1;
    u16* wlmT_h = w2T_l + SW1;     u16* wlmT_l = wlmT_h + SLM;

    // ---- weight prep: one dispatch for all five transpose/split jobs ----
    prep_weights<<<16320, 256, 0, stream>>>(Wq, Wk, Wv, Wo, W1, W2, Wlm,
                                            qkvT_h, qkvT_l, woT_h, woT_l,
                                            w1T_h, w1T_l, w2T_h, w2T_l,
                                            wlmT_h, wlmT_l);

    embed_kernel<<<NTOK, 128, 0, stream>>>(tokens, tok_emb, pos_emb, x);

    for (int l = 0; l < 4; ++l) {
        ln_split_kernel<<<NTOK / 4, 256, 0, stream>>>(x, ln1_g + l * EMB, ln1_b + l * EMB,
                                                      hhi, hlo);
        gemm_mfma<1, EPI_QKV><<<dim3(12, 64), 256, 0, stream>>>(
            hhi, hlo, qkvT_h + (size_t)l * 1536 * 512, qkvT_l + (size_t)l * 1536 * 512,
            nullptr, EMB, 1536, nullptr, qb16, kb16, vb16);

        attn_mfma<<<dim3(64, 16), 128, 0, stream>>>(qb16, kb16, vb16, ohi, olo);

        gemm_mfma<0, EPI_RES><<<dim3(8, 64), 256, 0, stream>>>(
            ohi, olo, woT_h + (size_t)l * 262144, woT_l + (size_t)l * 262144,
            bo + l * EMB, EMB, EMB, x, nullptr, nullptr, nullptr);

        ln_split_kernel<<<NTOK / 4, 256, 0, stream>>>(x, ln2_g + l * EMB, ln2_b + l * EMB,
                                                      hhi, hlo);
        gemm_mfma<2, EPI_RELU_SPLIT><<<dim3(16, 32), 256, 0, stream>>>(
            hhi, hlo, w1T_h + (size_t)l * 1048576, w1T_l + (size_t)l * 1048576,
            b1 + l * FFD, EMB, FFD, nullptr, ffhi, fflo, nullptr);

        gemm_mfma<0, EPI_RES><<<dim3(8, 64), 256, 0, stream>>>(
            ffhi, fflo, w2T_h + (size_t)l * 1048576, w2T_l + (size_t)l * 1048576,
            b2 + l * EMB, FFD, EMB, x, nullptr, nullptr, nullptr);
    }

    ln_split_kernel<<<NTOK / 4, 256, 0, stream>>>(x, lnf_g, lnf_b, hhi, hlo);

    gemm_mfma<2, EPI_OUT><<<dim3(63, 32), 256, 0, stream>>>(
        hhi, hlo, wlmT_h, wlmT_l, blm, EMB, VOCAB, out, nullptr, nullptr, nullptr);
}